// Round 1
// baseline (11115.644 us; speedup 1.0000x reference)
//
#include <hip/hip_runtime.h>
#include <hip/hip_bf16.h>
#include <math.h>

#define LN_EPS 1e-5f

// ---------- block reduction helpers (blockDim.x == 256, 4 waves) ----------
__device__ __forceinline__ float bred_sum(float v, float* red) {
  for (int o = 32; o; o >>= 1) v += __shfl_down(v, o, 64);
  int wid = threadIdx.x >> 6;
  __syncthreads();                       // protect red from previous use
  if ((threadIdx.x & 63) == 0) red[wid] = v;
  __syncthreads();
  return red[0] + red[1] + red[2] + red[3];
}
__device__ __forceinline__ float bred_max(float v, float* red) {
  for (int o = 32; o; o >>= 1) v = fmaxf(v, __shfl_down(v, o, 64));
  int wid = threadIdx.x >> 6;
  __syncthreads();
  if ((threadIdx.x & 63) == 0) red[wid] = v;
  __syncthreads();
  return fmaxf(fmaxf(red[0], red[1]), fmaxf(red[2], red[3]));
}

// ---------- folded BN params ----------
__global__ void fold_bn(const float* b1, const float* g1, const float* be1,
                        const float* m1, const float* v1,
                        const float* b2, const float* g2, const float* be2,
                        const float* m2, const float* v2,
                        float* s1, float* f1, float* s2, float* f2) {
  int t = blockIdx.x * 256 + threadIdx.x;
  if (t < 1024) { float s = g1[t] * rsqrtf(v1[t] + LN_EPS); s1[t] = s; f1[t] = (b1[t] - m1[t]) * s + be1[t]; }
  if (t < 512)  { float s = g2[t] * rsqrtf(v2[t] + LN_EPS); s2[t] = s; f2[t] = (b2[t] - m2[t]) * s + be2[t]; }
}

// ---------- generic tiled f32 GEMM ----------
// out[m,n] = sum_k a(m,k)*b(k,n); TA=1 -> A stored [K,M] (m contiguous);
// TB=1 -> B stored [N,K] (k contiguous). All of M%64==N%64==K%16==0.
// EPI: 0 none; 1 relu(acc*scale[m]+bias[m]); 2 acc*cscale; 3 acc+bias[n]
template<int TA, int TB, int EPI>
__global__ __launch_bounds__(256) void gemm_f32(
    const float* __restrict__ A, long sA, int lda,
    const float* __restrict__ B, long sB, int ldb,
    float* __restrict__ C, long sC, int ldc,
    int M, int N, int K,
    const float* __restrict__ ep_scale,
    const float* __restrict__ ep_bias,
    float cscale)
{
  __shared__ float As[16][68];
  __shared__ float Bs[16][68];
  int b = blockIdx.z;
  A += (long)b * sA; B += (long)b * sB; C += (long)b * sC;
  int tid = threadIdx.x;
  int tx = tid & 15, ty = tid >> 4;
  int bm = blockIdx.y * 64, bn = blockIdx.x * 64;
  float acc[4][4] = {};
  for (int k0 = 0; k0 < K; k0 += 16) {
#pragma unroll
    for (int i = 0; i < 4; i++) {
      int idx = tid + i * 256;
      if (TA == 0) { int m = idx >> 4, k = idx & 15; As[k][m] = A[(long)(bm + m) * lda + k0 + k]; }
      else         { int m = idx & 63, k = idx >> 6; As[k][m] = A[(long)(k0 + k) * lda + bm + m]; }
      if (TB == 0) { int n = idx & 63, k = idx >> 6; Bs[k][n] = B[(long)(k0 + k) * ldb + bn + n]; }
      else         { int n = idx >> 4, k = idx & 15; Bs[k][n] = B[(long)(bn + n) * ldb + k0 + k]; }
    }
    __syncthreads();
#pragma unroll
    for (int k = 0; k < 16; k++) {
      float4 a4 = *(const float4*)&As[k][ty * 4];
      float4 b4 = *(const float4*)&Bs[k][tx * 4];
      float av[4] = {a4.x, a4.y, a4.z, a4.w};
      float bv[4] = {b4.x, b4.y, b4.z, b4.w};
#pragma unroll
      for (int i = 0; i < 4; i++)
#pragma unroll
        for (int j = 0; j < 4; j++)
          acc[i][j] = fmaf(av[i], bv[j], acc[i][j]);
    }
    __syncthreads();
  }
#pragma unroll
  for (int i = 0; i < 4; i++) {
    int m = bm + ty * 4 + i;
#pragma unroll
    for (int j = 0; j < 4; j++) {
      int n = bn + tx * 4 + j;
      float v = acc[i][j];
      if (EPI == 1) v = fmaxf(fmaf(v, ep_scale[m], ep_bias[m]), 0.f);
      if (EPI == 2) v *= cscale;
      if (EPI == 3) v += ep_bias[n];
      C[(long)m * ldc + n] = v;
    }
  }
}

// ---------- 32x32 tiled transpose: src[R][Cc] -> dst[Cc][R], batched ----------
__global__ __launch_bounds__(256) void transpose_k(const float* __restrict__ src,
                                                   float* __restrict__ dst, int R, int Cc) {
  __shared__ float t[32][33];
  int b = blockIdx.z;
  src += (long)b * R * Cc; dst += (long)b * R * Cc;
  int c0 = blockIdx.x * 32, r0 = blockIdx.y * 32;
  int tx = threadIdx.x & 31, ty = threadIdx.x >> 5;  // 32 x 8
#pragma unroll
  for (int rr = 0; rr < 32; rr += 8) t[ty + rr][tx] = src[(long)(r0 + ty + rr) * Cc + c0 + tx];
  __syncthreads();
#pragma unroll
  for (int rr = 0; rr < 32; rr += 8) dst[(long)(c0 + ty + rr) * R + r0 + tx] = t[tx][ty + rr];
}

// ---------- in-place row softmax, row length PER*256 ----------
template<int PER>
__global__ __launch_bounds__(256) void row_softmax(float* __restrict__ x, long bstride) {
  __shared__ float red[4];
  const int L = PER * 256;
  int b = blockIdx.y, r = blockIdx.x, tid = threadIdx.x;
  float* p = x + (long)b * bstride + (long)r * L;
  float vals[PER];
  float mx = -1e30f;
#pragma unroll
  for (int t = 0; t < PER; t++) { float v = p[tid + (t << 8)]; vals[t] = v; mx = fmaxf(mx, v); }
  mx = bred_max(mx, red);
  float sm = 0.f;
#pragma unroll
  for (int t = 0; t < PER; t++) { float e = __expf(vals[t] - mx); vals[t] = e; sm += e; }
  sm = bred_sum(sm, red);
  float inv = 1.f / sm;
#pragma unroll
  for (int t = 0; t < PER; t++) p[tid + (t << 8)] = vals[t] * inv;
}

// ---------- attention core: scores in LDS, 2 queries / block ----------
// q,k,v,out: [B,S,512] compact; head h = cols [h*128,(h+1)*128)
__global__ __launch_bounds__(256) void attn_core(
    const float* __restrict__ q, const float* __restrict__ k,
    const float* __restrict__ v, float* __restrict__ out, int S)
{
  __shared__ float sc[2][3072];
  __shared__ float qs[2][128];
  __shared__ float red[4];
  int b = blockIdx.z, h = blockIdx.y;
  int q0 = blockIdx.x * 2;
  int tid = threadIdx.x;
  long base = (long)b * S * 512 + h * 128;
  {
    int r = tid >> 7, d = tid & 127;
    qs[r][d] = q[base + (long)(q0 + r) * 512 + d];
  }
  __syncthreads();
  const float scl = 0.044194173824159216f;  // 512^-0.5
  for (int kk = tid; kk < S; kk += 256) {
    const float* kr = k + base + (long)kk * 512;
    float d0 = 0.f, d1 = 0.f;
#pragma unroll 8
    for (int d = 0; d < 128; d += 4) {
      float4 kv = *(const float4*)&kr[d];
      float4 qa = *(const float4*)&qs[0][d];
      float4 qbv = *(const float4*)&qs[1][d];
      d0 += kv.x * qa.x + kv.y * qa.y + kv.z * qa.z + kv.w * qa.w;
      d1 += kv.x * qbv.x + kv.y * qbv.y + kv.z * qbv.z + kv.w * qbv.w;
    }
    sc[0][kk] = d0 * scl;
    sc[1][kk] = d1 * scl;
  }
  __syncthreads();
  float l0 = 0.f, l1 = 0.f;
#pragma unroll
  for (int r = 0; r < 2; r++) {
    float mx = -1e30f;
    for (int i2 = tid; i2 < S; i2 += 256) mx = fmaxf(mx, sc[r][i2]);
    mx = bred_max(mx, red);
    float sm = 0.f;
    for (int i2 = tid; i2 < S; i2 += 256) { float e = __expf(sc[r][i2] - mx); sc[r][i2] = e; sm += e; }
    float l = bred_sum(sm, red);   // barrier here makes all sc[r] writes visible
    if (r == 0) l0 = l; else l1 = l;
  }
  int g = tid >> 7, d = tid & 127;
  float linv = 1.f / ((tid < 128) ? l0 : l1);
  const float* vp = v + base + d;
  float o0 = 0.f, o1 = 0.f, o2 = 0.f, o3 = 0.f;
  for (int kk = 0; kk < S; kk += 4) {
    o0 = fmaf(sc[g][kk],     vp[(long)kk * 512],        o0);
    o1 = fmaf(sc[g][kk + 1], vp[(long)(kk + 1) * 512],  o1);
    o2 = fmaf(sc[g][kk + 2], vp[(long)(kk + 2) * 512],  o2);
    o3 = fmaf(sc[g][kk + 3], vp[(long)(kk + 3) * 512],  o3);
  }
  out[base + (long)(q0 + g) * 512 + d] = (o0 + o1 + o2 + o3) * linv;
}

// ---------- residual add + LayerNorm over E=512 ----------
// att: [B,S,512] compact. resid elem: resid + b*rb + s*rs + e*re. dst row: dst + b*db + s*512.
__global__ __launch_bounds__(256) void add_ln(
    const float* __restrict__ att, const float* __restrict__ resid,
    long rb, long rs, long re,
    const float* __restrict__ g, const float* __restrict__ bt,
    float* __restrict__ dst, long db, int S)
{
  __shared__ float red[4];
  int b = blockIdx.y, s = blockIdx.x, tid = threadIdx.x;
  const float* ap = att + ((long)b * S + s) * 512;
  const float* rp = resid + (long)b * rb + (long)s * rs;
  float y0 = ap[tid]       + rp[(long)tid * re];
  float y1 = ap[tid + 256] + rp[(long)(tid + 256) * re];
  float mu = bred_sum(y0 + y1, red) * (1.f / 512.f);
  float d0 = y0 - mu, d1 = y1 - mu;
  float var = bred_sum(d0 * d0 + d1 * d1, red) * (1.f / 512.f);
  float rsv = rsqrtf(var + LN_EPS);
  float* dp = dst + (long)b * db + (long)s * 512;
  dp[tid]       = d0 * rsv * g[tid]       + bt[tid];
  dp[tid + 256] = d1 * rsv * g[tid + 256] + bt[tid + 256];
}

extern "C" void kernel_launch(void* const* d_in, const int* in_sizes, int n_in,
                              void* d_out, int out_size, void* d_ws, size_t ws_size,
                              hipStream_t stream) {
  (void)in_sizes; (void)n_in; (void)out_size; (void)ws_size;
  const float* img = (const float*)d_in[0];
  const float* pts = (const float*)d_in[1];
  const float* w1  = (const float*)d_in[2];
  const float* b1  = (const float*)d_in[3];
  const float* g1  = (const float*)d_in[4];
  const float* be1 = (const float*)d_in[5];
  const float* m1  = (const float*)d_in[6];
  const float* v1  = (const float*)d_in[7];
  const float* w2  = (const float*)d_in[8];
  const float* b2  = (const float*)d_in[9];
  const float* g2  = (const float*)d_in[10];
  const float* be2 = (const float*)d_in[11];
  const float* m2  = (const float*)d_in[12];
  const float* v2  = (const float*)d_in[13];
  const float* qw  = (const float*)d_in[14];
  const float* qb  = (const float*)d_in[15];
  const float* kw  = (const float*)d_in[16];
  const float* kb  = (const float*)d_in[17];
  const float* vw  = (const float*)d_in[18];
  const float* vb  = (const float*)d_in[19];
  const float* lng = (const float*)d_in[20];
  const float* lnb = (const float*)d_in[21];
  float* out = (float*)d_out;
  float* ws  = (float*)d_ws;

  // ---- workspace arena (floats); total 39,848,960 f = ~159.4 MB ----
  float* feat   = ws;                  // [4,512,3072] (p cols 0..2047, i cols 2048..3071)
  float* y1b    = ws + 6291456;        // [4,1024,3072]; region later reused for phi
  float* phi    = y1b;                 // [4,2048,1024]
  float* phiT   = ws + 18874368;       // [4,1024,2048]
  float* attout = ws + 18874368;       // [4,<=3072,512] (reuses phiT region after I_enh)
  float* Ienh   = ws + 27262976;       // [4,512,1024]
  float* Penh   = ws + 29360128;       // [4,512,2048]
  float* qbuf   = ws;                  // [4,<=3072,512] (reuses feat after P_enh)
  float* kbuf   = ws + 6291456;        // (reuses y1b/phi)
  float* vbuf   = ws + 12582912;
  float* joint  = ws + 33554432;       // [4,3072,512]  (rows: P 0..2047, I 2048..3071)
  float* s1f    = ws + 39845888;
  float* f1f    = s1f + 1024;
  float* s2f    = f1f + 1024;
  float* f2f    = s2f + 512;

  dim3 blk(256);
  fold_bn<<<dim3(4), blk, 0, stream>>>(b1, g1, be1, m1, v1, b2, g2, be2, m2, v2, s1f, f1f, s2f, f2f);

  // ---- MLP layer 1: y1 = relu(bn1(w1 @ x)) ----
  gemm_f32<0,0,1><<<dim3(32,16,4), blk, 0, stream>>>(w1, 0, 512, pts, (long)512*2048, 2048,
      y1b, (long)1024*3072, 3072, 1024, 2048, 512, s1f, f1f, 0.f);
  gemm_f32<0,0,1><<<dim3(16,16,4), blk, 0, stream>>>(w1, 0, 512, img, (long)512*1024, 1024,
      y1b + 2048, (long)1024*3072, 3072, 1024, 1024, 512, s1f, f1f, 0.f);
  // ---- MLP layer 2: feat = relu(bn2(w2 @ y1)) ----
  gemm_f32<0,0,1><<<dim3(32,8,4), blk, 0, stream>>>(w2, 0, 1024, y1b, (long)1024*3072, 3072,
      feat, (long)512*3072, 3072, 512, 2048, 1024, s2f, f2f, 0.f);
  gemm_f32<0,0,1><<<dim3(16,8,4), blk, 0, stream>>>(w2, 0, 1024, y1b + 2048, (long)1024*3072, 3072,
      feat + 2048, (long)512*3072, 3072, 512, 1024, 1024, s2f, f2f, 0.f);

  // ---- phi = p_feat^T @ i_feat * C^-0.5 : [2048,1024] ----
  gemm_f32<1,0,2><<<dim3(16,32,4), blk, 0, stream>>>(feat, (long)512*3072, 3072,
      feat + 2048, (long)512*3072, 3072, phi, (long)2048*1024, 1024,
      2048, 1024, 512, nullptr, nullptr, 0.044194173824159216f);
  transpose_k<<<dim3(32,64,4), blk, 0, stream>>>(phi, phiT, 2048, 1024);
  row_softmax<4><<<dim3(2048,4), blk, 0, stream>>>(phi,  (long)2048*1024);  // phi_i (over i)
  row_softmax<8><<<dim3(1024,4), blk, 0, stream>>>(phiT, (long)2048*1024);  // phi_p^T (over p)

  // ---- I_enh = p_feat @ phi_p : [512,1024]; B = phiT as [N,K] ----
  gemm_f32<0,1,0><<<dim3(16,8,4), blk, 0, stream>>>(feat, (long)512*3072, 3072,
      phiT, (long)2048*1024, 2048, Ienh, (long)512*1024, 1024,
      512, 1024, 2048, nullptr, nullptr, 0.f);
  // ---- P_enh = i_feat @ phi_i^T : [512,2048]; B = phi as [N,K] ----
  gemm_f32<0,1,0><<<dim3(32,8,4), blk, 0, stream>>>(feat + 2048, (long)512*3072, 3072,
      phi, (long)2048*1024, 1024, Penh, (long)512*2048, 2048,
      512, 2048, 1024, nullptr, nullptr, 0.f);

  // ---- att0: X = Ienh [C,S], S=1024 -> joint rows 2048..3071 ----
  {
    const int S = 1024; const long xs = (long)512 * 1024; const int j = 0;
    gemm_f32<1,1,3><<<dim3(8,S/64,4), blk, 0, stream>>>(Ienh, xs, S, qw + j*262144, 0, 512,
        qbuf, (long)S*512, 512, S, 512, 512, nullptr, qb + j*512, 0.f);
    gemm_f32<1,1,3><<<dim3(8,S/64,4), blk, 0, stream>>>(Ienh, xs, S, kw + j*262144, 0, 512,
        kbuf, (long)S*512, 512, S, 512, 512, nullptr, kb + j*512, 0.f);
    gemm_f32<1,1,3><<<dim3(8,S/64,4), blk, 0, stream>>>(Ienh, xs, S, vw + j*262144, 0, 512,
        vbuf, (long)S*512, 512, S, 512, 512, nullptr, vb + j*512, 0.f);
    attn_core<<<dim3(S/2,4,4), blk, 0, stream>>>(qbuf, kbuf, vbuf, attout, S);
    add_ln<<<dim3(S,4), blk, 0, stream>>>(attout, Ienh, xs, 1L, (long)S,
        lng + j*512, lnb + j*512, joint + (long)2048*512, (long)3072*512, S);
  }
  // ---- att1: X = Penh [C,S], S=2048 -> joint rows 0..2047 ----
  {
    const int S = 2048; const long xs = (long)512 * 2048; const int j = 1;
    gemm_f32<1,1,3><<<dim3(8,S/64,4), blk, 0, stream>>>(Penh, xs, S, qw + j*262144, 0, 512,
        qbuf, (long)S*512, 512, S, 512, 512, nullptr, qb + j*512, 0.f);
    gemm_f32<1,1,3><<<dim3(8,S/64,4), blk, 0, stream>>>(Penh, xs, S, kw + j*262144, 0, 512,
        kbuf, (long)S*512, 512, S, 512, 512, nullptr, kb + j*512, 0.f);
    gemm_f32<1,1,3><<<dim3(8,S/64,4), blk, 0, stream>>>(Penh, xs, S, vw + j*262144, 0, 512,
        vbuf, (long)S*512, 512, S, 512, 512, nullptr, vb + j*512, 0.f);
    attn_core<<<dim3(S/2,4,4), blk, 0, stream>>>(qbuf, kbuf, vbuf, attout, S);
    add_ln<<<dim3(S,4), blk, 0, stream>>>(attout, Penh, xs, 1L, (long)S,
        lng + j*512, lnb + j*512, joint, (long)3072*512, S);
  }
  // ---- att2: X = joint [S,E], S=3072 -> d_out ----
  {
    const int S = 3072; const long xs = (long)3072 * 512; const int j = 2;
    gemm_f32<0,1,3><<<dim3(8,S/64,4), blk, 0, stream>>>(joint, xs, 512, qw + j*262144, 0, 512,
        qbuf, (long)S*512, 512, S, 512, 512, nullptr, qb + j*512, 0.f);
    gemm_f32<0,1,3><<<dim3(8,S/64,4), blk, 0, stream>>>(joint, xs, 512, kw + j*262144, 0, 512,
        kbuf, (long)S*512, 512, S, 512, 512, nullptr, kb + j*512, 0.f);
    gemm_f32<0,1,3><<<dim3(8,S/64,4), blk, 0, stream>>>(joint, xs, 512, vw + j*262144, 0, 512,
        vbuf, (long)S*512, 512, S, 512, 512, nullptr, vb + j*512, 0.f);
    attn_core<<<dim3(S/2,4,4), blk, 0, stream>>>(qbuf, kbuf, vbuf, attout, S);
    add_ln<<<dim3(S,4), blk, 0, stream>>>(attout, joint, xs, 512L, 1L,
        lng + j*512, lnb + j*512, out, (long)3072*512, S);
  }
}

// Round 2
// 727.778 us; speedup vs baseline: 15.2734x; 15.2734x over previous
//
#include <hip/hip_runtime.h>
#include <math.h>

#define LN_EPS 1e-5f

typedef __attribute__((ext_vector_type(8))) short bf16x8;
typedef __attribute__((ext_vector_type(4))) float f32x4;

__device__ __forceinline__ float b2f(unsigned short h) { return __uint_as_float(((unsigned)h) << 16); }
__device__ __forceinline__ unsigned short f2b(float f) {
  unsigned u = __float_as_uint(f);
  unsigned r = (u + 0x7fffu + ((u >> 16) & 1u)) >> 16;
  return (unsigned short)r;
}
__device__ __forceinline__ float ld(const float* p) { return *p; }
__device__ __forceinline__ float ld(const unsigned short* p) { return b2f(*p); }
__device__ __forceinline__ void st(float* p, float v) { *p = v; }
__device__ __forceinline__ void st(unsigned short* p, float v) { *p = f2b(v); }

// ---------- block reduction helpers (256 threads, 4 waves) ----------
__device__ __forceinline__ float bred_sum(float v, float* red) {
  for (int o = 32; o; o >>= 1) v += __shfl_down(v, o, 64);
  int wid = threadIdx.x >> 6;
  __syncthreads();
  if ((threadIdx.x & 63) == 0) red[wid] = v;
  __syncthreads();
  return red[0] + red[1] + red[2] + red[3];
}

// ---------- folded BN ----------
__global__ void fold_bn(const float* b1, const float* g1, const float* be1,
                        const float* m1, const float* v1,
                        const float* b2, const float* g2, const float* be2,
                        const float* m2, const float* v2,
                        float* s1, float* f1, float* s2, float* f2) {
  int t = blockIdx.x * 256 + threadIdx.x;
  if (t < 1024) { float s = g1[t] * rsqrtf(v1[t] + LN_EPS); s1[t] = s; f1[t] = (b1[t] - m1[t]) * s + be1[t]; }
  if (t < 512)  { float s = g2[t] * rsqrtf(v2[t] + LN_EPS); s2[t] = s; f2[t] = (b2[t] - m2[t]) * s + be2[t]; }
}

// ---------- f32 -> bf16 elementwise ----------
__global__ void cvt_bf16(const float* __restrict__ s, unsigned short* __restrict__ d, int n) {
  int i = blockIdx.x * 256 + threadIdx.x;
  if (i < n) d[i] = f2b(s[i]);
}

// ---------- 32x32 tiled transpose, typed: src[R][Cc] -> dst[Cc][R] ----------
template<typename TS, typename TD>
__global__ __launch_bounds__(256) void transpose_t(const TS* __restrict__ src,
    TD* __restrict__ dst, int R, int Cc, long sS, long sD) {
  __shared__ float t[32][33];
  src += (long)blockIdx.z * sS; dst += (long)blockIdx.z * sD;
  int c0 = blockIdx.x * 32, r0 = blockIdx.y * 32;
  int tx = threadIdx.x & 31, ty = threadIdx.x >> 5;
#pragma unroll
  for (int rr = 0; rr < 32; rr += 8) t[ty + rr][tx] = ld(&src[(long)(r0 + ty + rr) * Cc + c0 + tx]);
  __syncthreads();
#pragma unroll
  for (int rr = 0; rr < 32; rr += 8) st(&dst[(long)(c0 + ty + rr) * R + r0 + tx], t[tx][ty + rr]);
}

// ---------- row softmax f32 -> bf16, row length PER*256 ----------
template<int PER>
__global__ __launch_bounds__(256) void softmax_k(const float* __restrict__ x,
    unsigned short* __restrict__ y, long bstr) {
  __shared__ float red[4];
  const int L = PER * 256;
  int b = blockIdx.y, r = blockIdx.x, tid = threadIdx.x;
  const float* p = x + (long)b * bstr + (long)r * L;
  unsigned short* o = y + (long)b * bstr + (long)r * L;
  float vals[PER];
  float mx = -1e30f;
#pragma unroll
  for (int t = 0; t < PER; t++) { float v = p[tid + (t << 8)]; vals[t] = v; mx = fmaxf(mx, v); }
  for (int ofs = 32; ofs; ofs >>= 1) mx = fmaxf(mx, __shfl_down(mx, ofs, 64));
  int wid = tid >> 6;
  if ((tid & 63) == 0) red[wid] = mx;
  __syncthreads();
  mx = fmaxf(fmaxf(red[0], red[1]), fmaxf(red[2], red[3]));
  float sm = 0.f;
#pragma unroll
  for (int t = 0; t < PER; t++) { float e = __expf(vals[t] - mx); vals[t] = e; sm += e; }
  sm = bred_sum(sm, red);
  float inv = 1.f / sm;
#pragma unroll
  for (int t = 0; t < PER; t++) o[tid + (t << 8)] = f2b(vals[t] * inv);
}

// ---------- bf16 MFMA GEMM: C[m,n] = sum_k A[m,k]*B[n,k], both k-contig ----------
// 128x128 tile, 4 waves of 64x64, BK=64.
// EPI: 0 none; 1 relu(v*sc[n]+bi[n]); 2 v*cscale; 3 v+bi[n]; 4 v+bi[m]
template<int EPI, typename TC>
__global__ __launch_bounds__(256) void gemm_bf16(
    const unsigned short* __restrict__ A, long sA, int lda,
    const unsigned short* __restrict__ B, long sB, int ldb,
    TC* __restrict__ C, long sC, int ldc,
    int M, int N, int K,
    const float* __restrict__ sc, const float* __restrict__ bi, float cscale)
{
  __shared__ short As[128][72];
  __shared__ short Bs[128][72];
  const int tid = threadIdx.x;
  const int lane = tid & 63, wid = tid >> 6;
  const int wm = wid >> 1, wn = wid & 1;
  const int l15 = lane & 15, l4 = lane >> 4;
  const int bm = blockIdx.y * 128, bn = blockIdx.x * 128;
  A += (long)blockIdx.z * sA; B += (long)blockIdx.z * sB; C += (long)blockIdx.z * sC;
  f32x4 acc[4][4] = {};
  for (int k0 = 0; k0 < K; k0 += 64) {
#pragma unroll
    for (int i = 0; i < 4; i++) {
      int idx = tid + i * 256;
      int row = idx >> 3, c8 = (idx & 7) * 8;
      *(bf16x8*)&As[row][c8] = *(const bf16x8*)(A + (long)(bm + row) * lda + k0 + c8);
      *(bf16x8*)&Bs[row][c8] = *(const bf16x8*)(B + (long)(bn + row) * ldb + k0 + c8);
    }
    __syncthreads();
#pragma unroll
    for (int ks = 0; ks < 2; ks++) {
      bf16x8 af[4], bfr[4];
#pragma unroll
      for (int t = 0; t < 4; t++) {
        af[t]  = *(const bf16x8*)&As[wm * 64 + t * 16 + l15][l4 * 8 + ks * 32];
        bfr[t] = *(const bf16x8*)&Bs[wn * 64 + t * 16 + l15][l4 * 8 + ks * 32];
      }
#pragma unroll
      for (int i = 0; i < 4; i++)
#pragma unroll
        for (int j2 = 0; j2 < 4; j2++)
          acc[i][j2] = __builtin_amdgcn_mfma_f32_16x16x32_bf16(af[i], bfr[j2], acc[i][j2], 0, 0, 0);
    }
    __syncthreads();
  }
#pragma unroll
  for (int i = 0; i < 4; i++) {
#pragma unroll
    for (int j2 = 0; j2 < 4; j2++) {
      int n = bn + wn * 64 + j2 * 16 + l15;
#pragma unroll
      for (int j = 0; j < 4; j++) {
        int m = bm + wm * 64 + i * 16 + l4 * 4 + j;
        float v = acc[i][j2][j];
        if (EPI == 1) v = fmaxf(fmaf(v, sc[n], bi[n]), 0.f);
        if (EPI == 2) v *= cscale;
        if (EPI == 3) v += bi[n];
        if (EPI == 4) v += bi[m];
        st(&C[(long)m * ldc + n], v);
      }
    }
  }
}

// ---------- flash attention, bf16 MFMA, both matmuls operand-swapped ----------
// q,k: [B,S,512] bf16; vT: [B,512,S] bf16; out: [B,S,512] f32. 64 q-rows/block.
__global__ __launch_bounds__(256) void attn_flash(
    const unsigned short* __restrict__ q, const unsigned short* __restrict__ k,
    const unsigned short* __restrict__ vT, float* __restrict__ out, int S)
{
  __shared__ short Ks[64][136];
  __shared__ short Vs[128][72];
  __shared__ short Ps[4][16][72];
  const int tid = threadIdx.x, lane = tid & 63, wid = tid >> 6;
  const int h = blockIdx.y, b = blockIdx.z;
  const int l15 = lane & 15, l4 = lane >> 4;
  const long qkb = (long)b * S * 512;
  const long vbb = (long)b * 512 * S;
  const int qr0 = blockIdx.x * 64 + wid * 16;
  bf16x8 qf[4];
#pragma unroll
  for (int ks = 0; ks < 4; ks++)
    qf[ks] = *(const bf16x8*)(q + qkb + (long)(qr0 + l15) * 512 + h * 128 + l4 * 8 + ks * 32);
  f32x4 O[8] = {};
  float m_run = -1e30f, l_run = 0.f;
  const float scl = 0.044194173824159216f;  // 512^-0.5
  const int NT = S >> 6;
  for (int kt = 0; kt < NT; kt++) {
#pragma unroll
    for (int i = 0; i < 4; i++) {
      int idx = tid + i * 256;
      int kr = idx >> 4, kc = (idx & 15) * 8;
      *(bf16x8*)&Ks[kr][kc] = *(const bf16x8*)(k + qkb + (long)(kt * 64 + kr) * 512 + h * 128 + kc);
      int vr = idx >> 3, vc = (idx & 7) * 8;
      *(bf16x8*)&Vs[vr][vc] = *(const bf16x8*)(vT + vbb + (long)(h * 128 + vr) * S + kt * 64 + vc);
    }
    __syncthreads();
    // scores: sacc[f][j] = S[kv=f*16+l4*4+j][q=l15]
    f32x4 sacc[4] = {};
#pragma unroll
    for (int f = 0; f < 4; f++)
#pragma unroll
      for (int ks = 0; ks < 4; ks++) {
        bf16x8 kf = *(const bf16x8*)&Ks[f * 16 + l15][l4 * 8 + ks * 32];
        sacc[f] = __builtin_amdgcn_mfma_f32_16x16x32_bf16(kf, qf[ks], sacc[f], 0, 0, 0);
      }
    float pmax = -1e30f;
#pragma unroll
    for (int f = 0; f < 4; f++)
#pragma unroll
      for (int j = 0; j < 4; j++) { sacc[f][j] *= scl; pmax = fmaxf(pmax, sacc[f][j]); }
    pmax = fmaxf(pmax, __shfl_xor(pmax, 16, 64));
    pmax = fmaxf(pmax, __shfl_xor(pmax, 32, 64));
    float m_new = fmaxf(m_run, pmax);
    float corr = __expf(m_run - m_new);
    float ts = 0.f;
#pragma unroll
    for (int f = 0; f < 4; f++) {
      ushort4 pw;
#pragma unroll
      for (int j = 0; j < 4; j++) {
        float e = __expf(sacc[f][j] - m_new);
        ts += e;
        ((unsigned short*)&pw)[j] = f2b(e);
      }
      *(ushort4*)&Ps[wid][l15][f * 16 + l4 * 4] = pw;   // P[q][kv], wave-private
    }
    ts += __shfl_xor(ts, 16, 64);
    ts += __shfl_xor(ts, 32, 64);
    l_run = l_run * corr + ts;
    m_run = m_new;
#pragma unroll
    for (int fd = 0; fd < 8; fd++) {
      O[fd][0] *= corr; O[fd][1] *= corr; O[fd][2] *= corr; O[fd][3] *= corr;
    }
    // PV: O[d][q] += V^T[d][kv] * P[q][kv]
#pragma unroll
    for (int ks = 0; ks < 2; ks++) {
      bf16x8 pf = *(const bf16x8*)&Ps[wid][l15][l4 * 8 + ks * 32];
#pragma unroll
      for (int fd = 0; fd < 8; fd++) {
        bf16x8 vf = *(const bf16x8*)&Vs[fd * 16 + l15][l4 * 8 + ks * 32];
        O[fd] = __builtin_amdgcn_mfma_f32_16x16x32_bf16(vf, pf, O[fd], 0, 0, 0);
      }
    }
    __syncthreads();
  }
  float inv = 1.f / l_run;
  float* op = out + qkb + (long)(qr0 + l15) * 512 + h * 128;
#pragma unroll
  for (int fd = 0; fd < 8; fd++) {
    f32x4 ov = O[fd];
    ov[0] *= inv; ov[1] *= inv; ov[2] *= inv; ov[3] *= inv;
    *(f32x4*)&op[fd * 16 + l4 * 4] = ov;
  }
}

// ---------- residual add + LayerNorm over E=512 ----------
template<typename TD>
__global__ __launch_bounds__(256) void add_ln(
    const float* __restrict__ att, const unsigned short* __restrict__ resid,
    const float* __restrict__ g, const float* __restrict__ bt,
    TD* __restrict__ dst, long db, int S)
{
  __shared__ float red[4];
  int b = blockIdx.y, s = blockIdx.x, tid = threadIdx.x;
  const float* ap = att + ((long)b * S + s) * 512;
  const unsigned short* rp = resid + ((long)b * S + s) * 512;
  float y0 = ap[tid] + b2f(rp[tid]);
  float y1 = ap[tid + 256] + b2f(rp[tid + 256]);
  float mu = bred_sum(y0 + y1, red) * (1.f / 512.f);
  float d0 = y0 - mu, d1 = y1 - mu;
  float var = bred_sum(d0 * d0 + d1 * d1, red) * (1.f / 512.f);
  float rsv = rsqrtf(var + LN_EPS);
  TD* dp = dst + (long)b * db + (long)s * 512;
  st(&dp[tid], d0 * rsv * g[tid] + bt[tid]);
  st(&dp[tid + 256], d1 * rsv * g[tid + 256] + bt[tid + 256]);
}

extern "C" void kernel_launch(void* const* d_in, const int* in_sizes, int n_in,
                              void* d_out, int out_size, void* d_ws, size_t ws_size,
                              hipStream_t stream) {
  (void)in_sizes; (void)n_in; (void)out_size; (void)ws_size;
  const float* img = (const float*)d_in[0];
  const float* pts = (const float*)d_in[1];
  const float* w1  = (const float*)d_in[2];
  const float* b1  = (const float*)d_in[3];
  const float* g1  = (const float*)d_in[4];
  const float* be1 = (const float*)d_in[5];
  const float* m1  = (const float*)d_in[6];
  const float* v1  = (const float*)d_in[7];
  const float* w2  = (const float*)d_in[8];
  const float* b2  = (const float*)d_in[9];
  const float* g2  = (const float*)d_in[10];
  const float* be2 = (const float*)d_in[11];
  const float* m2  = (const float*)d_in[12];
  const float* v2  = (const float*)d_in[13];
  const float* qw  = (const float*)d_in[14];
  const float* qb  = (const float*)d_in[15];
  const float* kw  = (const float*)d_in[16];
  const float* kb  = (const float*)d_in[17];
  const float* vw  = (const float*)d_in[18];
  const float* vb  = (const float*)d_in[19];
  const float* lng = (const float*)d_in[20];
  const float* lnb = (const float*)d_in[21];
  float* out = (float*)d_out;
  float* ws  = (float*)d_ws;
  typedef unsigned short u16;

  // ---- arena (f32-slot offsets), total 39,455,744 f32 = 157.8 MB ----
  // Region A0 [0, 8388608): xT bf16 -> phi f32 -> attn qbuf/kbuf/vT
  // Region B0 [8388608, 16777216): y1 bf16 -> phiT f32 -> attn attout
  u16*   xTu   = (u16*)ws;                       // [4][3072][512] bf16
  float* phi   = ws;                             // [4][2048][1024] f32
  u16*   y1u   = (u16*)(ws + 8388608);           // [4][3072][1024] bf16
  float* phiT  = ws + 8388608;                   // [4][1024][2048] f32
  u16*   featu = (u16*)(ws + 16777216);          // [4][3072][512] bf16
  u16*   featTu= (u16*)(ws + 19922944);          // [4][512][3072] bf16
  u16*   smI   = (u16*)(ws + 23068672);          // phi_i softmax  [4][2048][1024] bf16
  u16*   smPT  = (u16*)(ws + 27262976);          // phi_p^T softmax [4][1024][2048] bf16
  u16*   Xi    = (u16*)(ws + 31457280);          // [4][1024][512] bf16
  u16*   Xp    = (u16*)(ws + 32505856);          // [4][2048][512] bf16
  u16*   jointu= (u16*)(ws + 34603008);          // [4][3072][512] bf16
  u16*   w1b   = (u16*)(ws + 37748736);
  u16*   w2b   = (u16*)(ws + 38010880);
  u16*   qwb   = (u16*)(ws + 38273024);
  u16*   kwb   = (u16*)(ws + 38666240);
  u16*   vwb   = (u16*)(ws + 39059456);
  float* s1f   = ws + 39452672;
  float* f1f   = s1f + 1024;
  float* s2f   = f1f + 1024;
  float* f2f   = s2f + 512;
  // attention scratch (inside A0+B0 after phi/phiT are dead)
  u16*   qbu   = (u16*)ws;                       // [4][S<=3072][512] bf16
  u16*   kbu   = (u16*)(ws + 3145728);
  u16*   vTu   = (u16*)(ws + 6291456);           // [4][512][S] bf16
  float* attf  = ws + 9437184;                   // [4][S][512] f32

  dim3 blk(256);
  fold_bn<<<dim3(4), blk, 0, stream>>>(b1, g1, be1, m1, v1, b2, g2, be2, m2, v2, s1f, f1f, s2f, f2f);
  cvt_bf16<<<dim3(2048), blk, 0, stream>>>(w1, w1b, 524288);
  cvt_bf16<<<dim3(2048), blk, 0, stream>>>(w2, w2b, 524288);
  cvt_bf16<<<dim3(3072), blk, 0, stream>>>(qw, qwb, 786432);
  cvt_bf16<<<dim3(3072), blk, 0, stream>>>(kw, kwb, 786432);
  cvt_bf16<<<dim3(3072), blk, 0, stream>>>(vw, vwb, 786432);

  // xT: [pos, 512] bf16 (points rows 0..2047, img rows 2048..3071)
  transpose_t<float, u16><<<dim3(64, 16, 4), blk, 0, stream>>>(pts, xTu, 512, 2048, 1048576L, 1572864L);
  transpose_t<float, u16><<<dim3(32, 16, 4), blk, 0, stream>>>(img, xTu + 1048576, 512, 1024, 524288L, 1572864L);

  // MLP1: y1[pos,1024] = relu(bn1(xT @ w1^T))
  gemm_bf16<1, u16><<<dim3(8, 24, 4), blk, 0, stream>>>(xTu, 1572864L, 512, w1b, 0L, 512,
      y1u, 3145728L, 1024, 3072, 1024, 512, s1f, f1f, 0.f);
  // MLP2: feat[pos,512]
  gemm_bf16<1, u16><<<dim3(4, 24, 4), blk, 0, stream>>>(y1u, 3145728L, 1024, w2b, 0L, 1024,
      featu, 1572864L, 512, 3072, 512, 1024, s2f, f2f, 0.f);
  // featT [512, 3072]
  transpose_t<u16, u16><<<dim3(16, 96, 4), blk, 0, stream>>>(featu, featTu, 3072, 512, 1572864L, 1572864L);
  // phi[p,i] f32
  gemm_bf16<2, float><<<dim3(8, 16, 4), blk, 0, stream>>>(featu, 1572864L, 512, featu + 1048576, 1572864L, 512,
      phi, 2097152L, 1024, 2048, 1024, 512, nullptr, nullptr, 0.044194173824159216f);
  transpose_t<float, float><<<dim3(32, 64, 4), blk, 0, stream>>>(phi, phiT, 2048, 1024, 2097152L, 2097152L);
  softmax_k<4><<<dim3(2048, 4), blk, 0, stream>>>(phi, smI, 2097152L);    // softmax over i
  softmax_k<8><<<dim3(1024, 4), blk, 0, stream>>>(phiT, smPT, 2097152L);  // softmax over p
  // Xi[i,c] = phi_p^T @ featP^T ; Xp[p,c] = phi_i @ featI^T
  gemm_bf16<0, u16><<<dim3(4, 8, 4), blk, 0, stream>>>(smPT, 2097152L, 2048, featTu, 1572864L, 3072,
      Xi, 524288L, 512, 1024, 512, 2048, nullptr, nullptr, 0.f);
  gemm_bf16<0, u16><<<dim3(4, 16, 4), blk, 0, stream>>>(smI, 2097152L, 1024, featTu + 2048, 1572864L, 3072,
      Xp, 1048576L, 512, 2048, 512, 1024, nullptr, nullptr, 0.f);

  struct AttCfg { const u16* X; int S; int j; };
  AttCfg cfgs[3] = { {Xi, 1024, 0}, {Xp, 2048, 1}, {jointu, 3072, 2} };
  for (int a = 0; a < 3; a++) {
    const u16* X = cfgs[a].X; int S = cfgs[a].S; int j = cfgs[a].j;
    long xs = (long)S * 512;
    gemm_bf16<3, u16><<<dim3(4, S / 128, 4), blk, 0, stream>>>(X, xs, 512, qwb + j * 262144, 0L, 512,
        qbu, xs, 512, S, 512, 512, nullptr, qb + j * 512, 0.f);
    gemm_bf16<3, u16><<<dim3(4, S / 128, 4), blk, 0, stream>>>(X, xs, 512, kwb + j * 262144, 0L, 512,
        kbu, xs, 512, S, 512, 512, nullptr, kb + j * 512, 0.f);
    gemm_bf16<4, u16><<<dim3(S / 128, 4, 4), blk, 0, stream>>>(vwb + j * 262144, 0L, 512, X, xs, 512,
        vTu, xs, S, 512, S, 512, nullptr, vb + j * 512, 0.f);
    attn_flash<<<dim3(S / 64, 4, 4), blk, 0, stream>>>(qbu, kbu, vTu, attf, S);
    if (a == 0)
      add_ln<u16><<<dim3(S, 4), blk, 0, stream>>>(attf, X, lng + j * 512, lnb + j * 512,
          jointu + 1048576, 1572864L, S);
    else if (a == 1)
      add_ln<u16><<<dim3(S, 4), blk, 0, stream>>>(attf, X, lng + j * 512, lnb + j * 512,
          jointu, 1572864L, S);
    else
      add_ln<float><<<dim3(S, 4), blk, 0, stream>>>(attf, X, lng + j * 512, lnb + j * 512,
          out, 1572864L, S);
  }
}

// Round 3
// 665.302 us; speedup vs baseline: 16.7077x; 1.0939x over previous
//
#include <hip/hip_runtime.h>
#include <math.h>

#define LN_EPS 1e-5f

typedef __attribute__((ext_vector_type(8))) short bf16x8;
typedef __attribute__((ext_vector_type(4))) float f32x4;

// async global->LDS, 16B per lane; LDS dest is wave-uniform base + lane*16
#define GLDS16(g, l) __builtin_amdgcn_global_load_lds( \
    (const __attribute__((address_space(1))) unsigned int*)(g), \
    (__attribute__((address_space(3))) unsigned int*)(l), 16, 0, 0)

__device__ __forceinline__ float b2f(unsigned short h) { return __uint_as_float(((unsigned)h) << 16); }
__device__ __forceinline__ unsigned short f2b(float f) {
  unsigned u = __float_as_uint(f);
  unsigned r = (u + 0x7fffu + ((u >> 16) & 1u)) >> 16;
  return (unsigned short)r;
}
__device__ __forceinline__ float ld(const float* p) { return *p; }
__device__ __forceinline__ float ld(const unsigned short* p) { return b2f(*p); }
__device__ __forceinline__ void st(float* p, float v) { *p = v; }
__device__ __forceinline__ void st(unsigned short* p, float v) { *p = f2b(v); }

// ---------- block reduction helpers (256 threads, 4 waves) ----------
__device__ __forceinline__ float bred_sum(float v, float* red) {
  for (int o = 32; o; o >>= 1) v += __shfl_down(v, o, 64);
  int wid = threadIdx.x >> 6;
  __syncthreads();
  if ((threadIdx.x & 63) == 0) red[wid] = v;
  __syncthreads();
  return red[0] + red[1] + red[2] + red[3];
}

// ---------- folded BN ----------
__global__ void fold_bn(const float* b1, const float* g1, const float* be1,
                        const float* m1, const float* v1,
                        const float* b2, const float* g2, const float* be2,
                        const float* m2, const float* v2,
                        float* s1, float* f1, float* s2, float* f2) {
  int t = blockIdx.x * 256 + threadIdx.x;
  if (t < 1024) { float s = g1[t] * rsqrtf(v1[t] + LN_EPS); s1[t] = s; f1[t] = (b1[t] - m1[t]) * s + be1[t]; }
  if (t < 512)  { float s = g2[t] * rsqrtf(v2[t] + LN_EPS); s2[t] = s; f2[t] = (b2[t] - m2[t]) * s + be2[t]; }
}

// ---------- f32 -> bf16 elementwise ----------
__global__ void cvt_bf16(const float* __restrict__ s, unsigned short* __restrict__ d, int n) {
  int i = blockIdx.x * 256 + threadIdx.x;
  if (i < n) d[i] = f2b(s[i]);
}

// ---------- 32x32 tiled transpose, typed: src[R][Cc] -> dst[Cc][R] ----------
template<typename TS, typename TD>
__global__ __launch_bounds__(256) void transpose_t(const TS* __restrict__ src,
    TD* __restrict__ dst, int R, int Cc, long sS, long sD) {
  __shared__ float t[32][33];
  src += (long)blockIdx.z * sS; dst += (long)blockIdx.z * sD;
  int c0 = blockIdx.x * 32, r0 = blockIdx.y * 32;
  int tx = threadIdx.x & 31, ty = threadIdx.x >> 5;
#pragma unroll
  for (int rr = 0; rr < 32; rr += 8) t[ty + rr][tx] = ld(&src[(long)(r0 + ty + rr) * Cc + c0 + tx]);
  __syncthreads();
#pragma unroll
  for (int rr = 0; rr < 32; rr += 8) st(&dst[(long)(c0 + ty + rr) * R + r0 + tx], t[tx][ty + rr]);
}

// ---------- row softmax f32 -> bf16, row length PER*256 ----------
template<int PER>
__global__ __launch_bounds__(256) void softmax_k(const float* __restrict__ x,
    unsigned short* __restrict__ y, long bstr) {
  __shared__ float red[4];
  const int L = PER * 256;
  int b = blockIdx.y, r = blockIdx.x, tid = threadIdx.x;
  const float* p = x + (long)b * bstr + (long)r * L;
  unsigned short* o = y + (long)b * bstr + (long)r * L;
  float vals[PER];
  float mx = -1e30f;
#pragma unroll
  for (int t = 0; t < PER; t++) { float v = p[tid + (t << 8)]; vals[t] = v; mx = fmaxf(mx, v); }
  for (int ofs = 32; ofs; ofs >>= 1) mx = fmaxf(mx, __shfl_down(mx, ofs, 64));
  int wid = tid >> 6;
  if ((tid & 63) == 0) red[wid] = mx;
  __syncthreads();
  mx = fmaxf(fmaxf(red[0], red[1]), fmaxf(red[2], red[3]));
  float sm = 0.f;
#pragma unroll
  for (int t = 0; t < PER; t++) { float e = __expf(vals[t] - mx); vals[t] = e; sm += e; }
  sm = bred_sum(sm, red);
  float inv = 1.f / sm;
#pragma unroll
  for (int t = 0; t < PER; t++) o[tid + (t << 8)] = f2b(vals[t] * inv);
}

// ---------- bf16 MFMA GEMM: C[m,n] = sum_k A[m,k]*B[n,k], both k-contig ----------
// 128x128 tile, 4 waves of 64x64, BK=64. global_load_lds staging with
// XOR-swizzled global source (linear LDS dest) + swizzled reads.
// EPI: 0 none; 1 relu(v*sc[n]+bi[n]); 2 v*cscale; 3 v+bi[n]; 4 v+bi[m]; 5 (v+bi[n])*cscale
template<int EPI, typename TC>
__global__ __launch_bounds__(256) void gemm_bf16(
    const unsigned short* __restrict__ A, long sA, int lda,
    const unsigned short* __restrict__ B, long sB, int ldb,
    TC* __restrict__ C, long sC, int ldc,
    int M, int N, int K,
    const float* __restrict__ sc, const float* __restrict__ bi, float cscale)
{
  __shared__ short As[128 * 64];
  __shared__ short Bs[128 * 64];
  const int tid = threadIdx.x;
  const int lane = tid & 63, wid = tid >> 6;
  const int wm = wid >> 1, wn = wid & 1;
  const int l15 = lane & 15, l4 = lane >> 4, l7 = lane & 7;
  const int bm = blockIdx.y * 128, bn = blockIdx.x * 128;
  const int srow = lane >> 3;           // 0..7 within staged 8-row group
  A += (long)blockIdx.z * sA; B += (long)blockIdx.z * sB; C += (long)blockIdx.z * sC;
  f32x4 acc[4][4] = {};
  for (int k0 = 0; k0 < K; k0 += 64) {
#pragma unroll
    for (int i = 0; i < 4; i++) {
      int row = (wid * 4 + i) * 8 + srow;             // tile row 0..127
      int gcol = (l7 ^ (row & 7)) * 8;                // swizzled k-chunk
      GLDS16(A + (long)(bm + row) * lda + k0 + gcol, &As[(wid * 4 + i) * 512]);
      GLDS16(B + (long)(bn + row) * ldb + k0 + gcol, &Bs[(wid * 4 + i) * 512]);
    }
    __syncthreads();
#pragma unroll
    for (int ks = 0; ks < 2; ks++) {
      bf16x8 af[4], bfr[4];
#pragma unroll
      for (int t = 0; t < 4; t++) {
        int ra = wm * 64 + t * 16 + l15;
        int rb = wn * 64 + t * 16 + l15;
        int ch = (l4 + 4 * ks) ^ (l15 & 7);
        af[t]  = *(const bf16x8*)&As[ra * 64 + ch * 8];
        bfr[t] = *(const bf16x8*)&Bs[rb * 64 + ch * 8];
      }
#pragma unroll
      for (int i = 0; i < 4; i++)
#pragma unroll
        for (int j2 = 0; j2 < 4; j2++)
          acc[i][j2] = __builtin_amdgcn_mfma_f32_16x16x32_bf16(af[i], bfr[j2], acc[i][j2], 0, 0, 0);
    }
    __syncthreads();
  }
#pragma unroll
  for (int i = 0; i < 4; i++) {
#pragma unroll
    for (int j2 = 0; j2 < 4; j2++) {
      int n = bn + wn * 64 + j2 * 16 + l15;
#pragma unroll
      for (int j = 0; j < 4; j++) {
        int m = bm + wm * 64 + i * 16 + l4 * 4 + j;
        float v = acc[i][j2][j];
        if (EPI == 1) v = fmaxf(fmaf(v, sc[n], bi[n]), 0.f);
        if (EPI == 2) v *= cscale;
        if (EPI == 3) v += bi[n];
        if (EPI == 4) v += bi[m];
        if (EPI == 5) v = (v + bi[n]) * cscale;
        st(&C[(long)m * ldc + n], v);
      }
    }
  }
}

// ---------- flash attention, bf16 MFMA, operand-swapped, 32 q-rows/wave ----------
// q,k: [B,S,512] bf16 (q pre-scaled by 512^-0.5); vT: [B,512,S] bf16; out: [B,S,512] f32.
__global__ __launch_bounds__(256) void attn_flash(
    const unsigned short* __restrict__ q, const unsigned short* __restrict__ k,
    const unsigned short* __restrict__ vT, float* __restrict__ out, int S)
{
  __shared__ short Ks[64 * 128];      // [kv][d], XOR-swizzled 16B chunks
  __shared__ short Vs[128 * 64];      // [d][kv], XOR-swizzled
  __shared__ short Ps[4][2][1024];    // per-wave [qg][16 q][64 kv], XOR-swizzled
  const int tid = threadIdx.x, lane = tid & 63, wid = tid >> 6;
  const int h = blockIdx.y, b = blockIdx.z;
  const int l15 = lane & 15, l4 = lane >> 4, l7 = l15 & 7;
  const long qkb = (long)b * S * 512;
  const long vbb = (long)b * 512 * S;
  const int qr0 = blockIdx.x * 128 + wid * 32;
  const int kr = lane >> 4, kc = lane & 15;   // K staging: 4 rows x 16 chunks
  const int vr = lane >> 3, vc = lane & 7;    // V staging: 8 rows x 8 chunks
  bf16x8 qf[2][4];
#pragma unroll
  for (int qg = 0; qg < 2; qg++)
#pragma unroll
    for (int ks = 0; ks < 4; ks++)
      qf[qg][ks] = *(const bf16x8*)(q + qkb + (long)(qr0 + qg * 16 + l15) * 512 + h * 128 + l4 * 8 + ks * 32);
  f32x4 O[2][8] = {};
  float m_run[2] = {-1e30f, -1e30f}, l_run[2] = {0.f, 0.f};
  const int NT = S >> 6;
  for (int kt = 0; kt < NT; kt++) {
#pragma unroll
    for (int i = 0; i < 4; i++) {
      int krow = wid * 16 + i * 4 + kr;
      GLDS16(k + qkb + (long)(kt * 64 + krow) * 512 + h * 128 + ((kc ^ (krow & 7)) << 3),
             &Ks[(wid * 16 + i * 4) * 128]);
      int vrow = wid * 32 + i * 8 + vr;
      GLDS16(vT + vbb + (long)(h * 128 + vrow) * S + kt * 64 + ((vc ^ (vrow & 7)) << 3),
             &Vs[(wid * 32 + i * 8) * 64]);
    }
    __syncthreads();
    // QK^T (swapped): sacc[qg][f][j] = S[kv = f*16 + l4*4 + j][q = l15]
    f32x4 sacc[2][4] = {};
#pragma unroll
    for (int f = 0; f < 4; f++) {
      int row = f * 16 + l15;
#pragma unroll
      for (int ks = 0; ks < 4; ks++) {
        bf16x8 kf = *(const bf16x8*)&Ks[row * 128 + (((l4 + 4 * ks) ^ l7) << 3)];
        sacc[0][f] = __builtin_amdgcn_mfma_f32_16x16x32_bf16(kf, qf[0][ks], sacc[0][f], 0, 0, 0);
        sacc[1][f] = __builtin_amdgcn_mfma_f32_16x16x32_bf16(kf, qf[1][ks], sacc[1][f], 0, 0, 0);
      }
    }
    float pmax[2] = {-1e30f, -1e30f};
#pragma unroll
    for (int qg = 0; qg < 2; qg++) {
#pragma unroll
      for (int f = 0; f < 4; f++)
#pragma unroll
        for (int j = 0; j < 4; j++) pmax[qg] = fmaxf(pmax[qg], sacc[qg][f][j]);
      pmax[qg] = fmaxf(pmax[qg], __shfl_xor(pmax[qg], 16, 64));
      pmax[qg] = fmaxf(pmax[qg], __shfl_xor(pmax[qg], 32, 64));
    }
    // defer-max: only rescale when some row's max grew past threshold
    if (!__all((pmax[0] - m_run[0] <= 8.f) && (pmax[1] - m_run[1] <= 8.f))) {
#pragma unroll
      for (int qg = 0; qg < 2; qg++) {
        float m_new = fmaxf(m_run[qg], pmax[qg]);
        float corr = __expf(m_run[qg] - m_new);
        l_run[qg] *= corr; m_run[qg] = m_new;
#pragma unroll
        for (int fd = 0; fd < 8; fd++) {
          O[qg][fd][0] *= corr; O[qg][fd][1] *= corr;
          O[qg][fd][2] *= corr; O[qg][fd][3] *= corr;
        }
      }
    }
#pragma unroll
    for (int qg = 0; qg < 2; qg++) {
      float ts = 0.f;
#pragma unroll
      for (int f = 0; f < 4; f++) {
        ushort4 pw;
#pragma unroll
        for (int j = 0; j < 4; j++) {
          float e = __expf(sacc[qg][f][j] - m_run[qg]);
          ts += e;
          ((unsigned short*)&pw)[j] = f2b(e);
        }
        *(ushort4*)&Ps[wid][qg][l15 * 64 + (((2 * f + (l4 >> 1)) ^ l7) << 3) + (l4 & 1) * 4] = pw;
      }
      ts += __shfl_xor(ts, 16, 64);
      ts += __shfl_xor(ts, 32, 64);
      l_run[qg] += ts;
    }
    // PV (swapped): O[qg][fd] += V^T[d][kv] * P[q][kv]
#pragma unroll
    for (int ks = 0; ks < 2; ks++) {
      int pch = ((l4 + 4 * ks) ^ l7) << 3;
      bf16x8 pf0 = *(const bf16x8*)&Ps[wid][0][l15 * 64 + pch];
      bf16x8 pf1 = *(const bf16x8*)&Ps[wid][1][l15 * 64 + pch];
#pragma unroll
      for (int fd = 0; fd < 8; fd++) {
        int row = fd * 16 + l15;
        bf16x8 vf = *(const bf16x8*)&Vs[row * 64 + (((l4 + 4 * ks) ^ l7) << 3)];
        O[0][fd] = __builtin_amdgcn_mfma_f32_16x16x32_bf16(vf, pf0, O[0][fd], 0, 0, 0);
        O[1][fd] = __builtin_amdgcn_mfma_f32_16x16x32_bf16(vf, pf1, O[1][fd], 0, 0, 0);
      }
    }
    __syncthreads();
  }
#pragma unroll
  for (int qg = 0; qg < 2; qg++) {
    float inv = 1.f / l_run[qg];
    float* op = out + qkb + (long)(qr0 + qg * 16 + l15) * 512 + h * 128;
#pragma unroll
    for (int fd = 0; fd < 8; fd++) {
      f32x4 ov = O[qg][fd];
      ov[0] *= inv; ov[1] *= inv; ov[2] *= inv; ov[3] *= inv;
      *(f32x4*)&op[fd * 16 + l4 * 4] = ov;
    }
  }
}

// ---------- residual add + LayerNorm over E=512 ----------
template<typename TD>
__global__ __launch_bounds__(256) void add_ln(
    const float* __restrict__ att, const unsigned short* __restrict__ resid,
    const float* __restrict__ g, const float* __restrict__ bt,
    TD* __restrict__ dst, long db, int S)
{
  __shared__ float red[4];
  int b = blockIdx.y, s = blockIdx.x, tid = threadIdx.x;
  const float* ap = att + ((long)b * S + s) * 512;
  const unsigned short* rp = resid + ((long)b * S + s) * 512;
  float y0 = ap[tid] + b2f(rp[tid]);
  float y1 = ap[tid + 256] + b2f(rp[tid + 256]);
  float mu = bred_sum(y0 + y1, red) * (1.f / 512.f);
  float d0 = y0 - mu, d1 = y1 - mu;
  float var = bred_sum(d0 * d0 + d1 * d1, red) * (1.f / 512.f);
  float rsv = rsqrtf(var + LN_EPS);
  TD* dp = dst + (long)b * db + (long)s * 512;
  st(&dp[tid], d0 * rsv * g[tid] + bt[tid]);
  st(&dp[tid + 256], d1 * rsv * g[tid + 256] + bt[tid + 256]);
}

extern "C" void kernel_launch(void* const* d_in, const int* in_sizes, int n_in,
                              void* d_out, int out_size, void* d_ws, size_t ws_size,
                              hipStream_t stream) {
  (void)in_sizes; (void)n_in; (void)out_size; (void)ws_size;
  const float* img = (const float*)d_in[0];
  const float* pts = (const float*)d_in[1];
  const float* w1  = (const float*)d_in[2];
  const float* b1  = (const float*)d_in[3];
  const float* g1  = (const float*)d_in[4];
  const float* be1 = (const float*)d_in[5];
  const float* m1  = (const float*)d_in[6];
  const float* v1  = (const float*)d_in[7];
  const float* w2  = (const float*)d_in[8];
  const float* b2  = (const float*)d_in[9];
  const float* g2  = (const float*)d_in[10];
  const float* be2 = (const float*)d_in[11];
  const float* m2  = (const float*)d_in[12];
  const float* v2  = (const float*)d_in[13];
  const float* qw  = (const float*)d_in[14];
  const float* qb  = (const float*)d_in[15];
  const float* kw  = (const float*)d_in[16];
  const float* kb  = (const float*)d_in[17];
  const float* vw  = (const float*)d_in[18];
  const float* vb  = (const float*)d_in[19];
  const float* lng = (const float*)d_in[20];
  const float* lnb = (const float*)d_in[21];
  float* out = (float*)d_out;
  float* ws  = (float*)d_ws;
  typedef unsigned short u16;

  // ---- arena (f32-slot offsets), total ~157.8 MB ----
  u16*   xTu   = (u16*)ws;                       // [4][3072][512] bf16
  float* phi   = ws;                             // [4][2048][1024] f32
  u16*   y1u   = (u16*)(ws + 8388608);           // [4][3072][1024] bf16
  float* phiT  = ws + 8388608;                   // [4][1024][2048] f32
  u16*   featu = (u16*)(ws + 16777216);          // [4][3072][512] bf16
  u16*   featTu= (u16*)(ws + 19922944);          // [4][512][3072] bf16
  u16*   smI   = (u16*)(ws + 23068672);          // phi_i softmax  [4][2048][1024] bf16
  u16*   smPT  = (u16*)(ws + 27262976);          // phi_p^T softmax [4][1024][2048] bf16
  u16*   Xi    = (u16*)(ws + 31457280);          // [4][1024][512] bf16
  u16*   Xp    = (u16*)(ws + 32505856);          // [4][2048][512] bf16
  u16*   jointu= (u16*)(ws + 34603008);          // [4][3072][512] bf16
  u16*   w1b   = (u16*)(ws + 37748736);
  u16*   w2b   = (u16*)(ws + 38010880);
  u16*   qwb   = (u16*)(ws + 38273024);
  u16*   kwb   = (u16*)(ws + 38666240);
  u16*   vwb   = (u16*)(ws + 39059456);
  float* s1f   = ws + 39452672;
  float* f1f   = s1f + 1024;
  float* s2f   = f1f + 1024;
  float* f2f   = s2f + 512;
  // attention scratch (A0/B0 regions after phi/phiT are dead)
  u16*   qbu   = (u16*)ws;                       // [4][S<=3072][512] bf16
  u16*   kbu   = (u16*)(ws + 3145728);
  u16*   vTu   = (u16*)(ws + 6291456);           // [4][512][S] bf16
  float* attf  = ws + 9437184;                   // [4][S][512] f32

  dim3 blk(256);
  fold_bn<<<dim3(4), blk, 0, stream>>>(b1, g1, be1, m1, v1, b2, g2, be2, m2, v2, s1f, f1f, s2f, f2f);
  cvt_bf16<<<dim3(2048), blk, 0, stream>>>(w1, w1b, 524288);
  cvt_bf16<<<dim3(2048), blk, 0, stream>>>(w2, w2b, 524288);
  cvt_bf16<<<dim3(3072), blk, 0, stream>>>(qw, qwb, 786432);
  cvt_bf16<<<dim3(3072), blk, 0, stream>>>(kw, kwb, 786432);
  cvt_bf16<<<dim3(3072), blk, 0, stream>>>(vw, vwb, 786432);

  // xT: [pos, 512] bf16 (points rows 0..2047, img rows 2048..3071)
  transpose_t<float, u16><<<dim3(64, 16, 4), blk, 0, stream>>>(pts, xTu, 512, 2048, 1048576L, 1572864L);
  transpose_t<float, u16><<<dim3(32, 16, 4), blk, 0, stream>>>(img, xTu + 1048576, 512, 1024, 524288L, 1572864L);

  // MLP1: y1[pos,1024] = relu(bn1(xT @ w1^T))
  gemm_bf16<1, u16><<<dim3(8, 24, 4), blk, 0, stream>>>(xTu, 1572864L, 512, w1b, 0L, 512,
      y1u, 3145728L, 1024, 3072, 1024, 512, s1f, f1f, 0.f);
  // MLP2: feat[pos,512]
  gemm_bf16<1, u16><<<dim3(4, 24, 4), blk, 0, stream>>>(y1u, 3145728L, 1024, w2b, 0L, 1024,
      featu, 1572864L, 512, 3072, 512, 1024, s2f, f2f, 0.f);
  // featT [512, 3072]
  transpose_t<u16, u16><<<dim3(16, 96, 4), blk, 0, stream>>>(featu, featTu, 3072, 512, 1572864L, 1572864L);
  // phi[p,i] f32
  gemm_bf16<2, float><<<dim3(8, 16, 4), blk, 0, stream>>>(featu, 1572864L, 512, featu + 1048576, 1572864L, 512,
      phi, 2097152L, 1024, 2048, 1024, 512, nullptr, nullptr, 0.044194173824159216f);
  transpose_t<float, float><<<dim3(32, 64, 4), blk, 0, stream>>>(phi, phiT, 2048, 1024, 2097152L, 2097152L);
  softmax_k<4><<<dim3(2048, 4), blk, 0, stream>>>(phi, smI, 2097152L);    // softmax over i
  softmax_k<8><<<dim3(1024, 4), blk, 0, stream>>>(phiT, smPT, 2097152L);  // softmax over p
  // Xi[i,c] = phi_p^T @ featP^T ; Xp[p,c] = phi_i @ featI^T
  gemm_bf16<0, u16><<<dim3(4, 8, 4), blk, 0, stream>>>(smPT, 2097152L, 2048, featTu, 1572864L, 3072,
      Xi, 524288L, 512, 1024, 512, 2048, nullptr, nullptr, 0.f);
  gemm_bf16<0, u16><<<dim3(4, 16, 4), blk, 0, stream>>>(smI, 2097152L, 1024, featTu + 2048, 1572864L, 3072,
      Xp, 1048576L, 512, 2048, 512, 1024, nullptr, nullptr, 0.f);

  const float scl = 0.044194173824159216f;  // 512^-0.5, folded into Q projection
  struct AttCfg { const u16* X; int S; int j; };
  AttCfg cfgs[3] = { {Xi, 1024, 0}, {Xp, 2048, 1}, {jointu, 3072, 2} };
  for (int a = 0; a < 3; a++) {
    const u16* X = cfgs[a].X; int S = cfgs[a].S; int j = cfgs[a].j;
    long xs = (long)S * 512;
    gemm_bf16<5, u16><<<dim3(4, S / 128, 4), blk, 0, stream>>>(X, xs, 512, qwb + j * 262144, 0L, 512,
        qbu, xs, 512, S, 512, 512, nullptr, qb + j * 512, scl);
    gemm_bf16<3, u16><<<dim3(4, S / 128, 4), blk, 0, stream>>>(X, xs, 512, kwb + j * 262144, 0L, 512,
        kbu, xs, 512, S, 512, 512, nullptr, kb + j * 512, 0.f);
    gemm_bf16<4, u16><<<dim3(S / 128, 4, 4), blk, 0, stream>>>(vwb + j * 262144, 0L, 512, X, xs, 512,
        vTu, xs, S, 512, S, 512, nullptr, vb + j * 512, 0.f);
    attn_flash<<<dim3(S / 128, 4, 4), blk, 0, stream>>>(qbu, kbu, vTu, attf, S);
    if (a == 0)
      add_ln<u16><<<dim3(S, 4), blk, 0, stream>>>(attf, X, lng + j * 512, lnb + j * 512,
          jointu + 1048576, 1572864L, S);
    else if (a == 1)
      add_ln<u16><<<dim3(S, 4), blk, 0, stream>>>(attf, X, lng + j * 512, lnb + j * 512,
          jointu, 1572864L, S);
    else
      add_ln<float><<<dim3(S, 4), blk, 0, stream>>>(attf, X, lng + j * 512, lnb + j * 512,
          out, 1572864L, S);
  }
}

// Round 4
// 591.284 us; speedup vs baseline: 18.7992x; 1.1252x over previous
//
#include <hip/hip_runtime.h>
#include <math.h>

#define LN_EPS 1e-5f

typedef __attribute__((ext_vector_type(8))) short bf16x8;
typedef __attribute__((ext_vector_type(4))) float f32x4;

// async global->LDS, 16B per lane; LDS dest is wave-uniform base + lane*16
#define GLDS16(g, l) __builtin_amdgcn_global_load_lds( \
    (const __attribute__((address_space(1))) unsigned int*)(g), \
    (__attribute__((address_space(3))) unsigned int*)(l), 16, 0, 0)

__device__ __forceinline__ float b2f(unsigned short h) { return __uint_as_float(((unsigned)h) << 16); }
__device__ __forceinline__ unsigned short f2b(float f) {
  unsigned u = __float_as_uint(f);
  unsigned r = (u + 0x7fffu + ((u >> 16) & 1u)) >> 16;
  return (unsigned short)r;
}
__device__ __forceinline__ float ld(const float* p) { return *p; }
__device__ __forceinline__ float ld(const unsigned short* p) { return b2f(*p); }
__device__ __forceinline__ void st(float* p, float v) { *p = v; }
__device__ __forceinline__ void st(unsigned short* p, float v) { *p = f2b(v); }

// ---------- block reduction helpers (256 threads, 4 waves) ----------
__device__ __forceinline__ float bred_sum(float v, float* red) {
  for (int o = 32; o; o >>= 1) v += __shfl_down(v, o, 64);
  int wid = threadIdx.x >> 6;
  __syncthreads();
  if ((threadIdx.x & 63) == 0) red[wid] = v;
  __syncthreads();
  return red[0] + red[1] + red[2] + red[3];
}

// ---------- folded BN ----------
__global__ void fold_bn(const float* b1, const float* g1, const float* be1,
                        const float* m1, const float* v1,
                        const float* b2, const float* g2, const float* be2,
                        const float* m2, const float* v2,
                        float* s1, float* f1, float* s2, float* f2) {
  int t = blockIdx.x * 256 + threadIdx.x;
  if (t < 1024) { float s = g1[t] * rsqrtf(v1[t] + LN_EPS); s1[t] = s; f1[t] = (b1[t] - m1[t]) * s + be1[t]; }
  if (t < 512)  { float s = g2[t] * rsqrtf(v2[t] + LN_EPS); s2[t] = s; f2[t] = (b2[t] - m2[t]) * s + be2[t]; }
}

// ---------- f32 -> bf16 elementwise ----------
__global__ void cvt_bf16(const float* __restrict__ s, unsigned short* __restrict__ d, int n) {
  int i = blockIdx.x * 256 + threadIdx.x;
  if (i < n) d[i] = f2b(s[i]);
}

// ---------- build concatenated QK weights/bias, q-side prescaled by 512^-0.5 ----------
__global__ void prep_qk(const float* __restrict__ qw, const float* __restrict__ qb,
                        const float* __restrict__ kw, const float* __restrict__ kb,
                        unsigned short* __restrict__ qkw, float* __restrict__ qkbias) {
  const float scl = 0.044194173824159216f;
  int idx = blockIdx.x * 256 + threadIdx.x;   // over 3*1024*512
  if (idx < 1572864) {
    int j = idx >> 19; int r = idx & 524287; int n = r >> 9; int k = r & 511;
    float v = (n < 512) ? qw[j * 262144 + n * 512 + k] * scl
                        : kw[j * 262144 + (n - 512) * 512 + k];
    qkw[idx] = f2b(v);
  }
  if (idx < 3072) {
    int j = idx >> 10, n = idx & 1023;
    qkbias[idx] = (n < 512) ? qb[j * 512 + n] * scl : kb[j * 512 + n - 512];
  }
}

// ---------- 32x32 tiled transpose, typed: src[R][Cc] -> dst[Cc][R] ----------
template<typename TS, typename TD>
__global__ __launch_bounds__(256) void transpose_t(const TS* __restrict__ src,
    TD* __restrict__ dst, int R, int Cc, long sS, long sD) {
  __shared__ float t[32][33];
  src += (long)blockIdx.z * sS; dst += (long)blockIdx.z * sD;
  int c0 = blockIdx.x * 32, r0 = blockIdx.y * 32;
  int tx = threadIdx.x & 31, ty = threadIdx.x >> 5;
#pragma unroll
  for (int rr = 0; rr < 32; rr += 8) t[ty + rr][tx] = ld(&src[(long)(r0 + ty + rr) * Cc + c0 + tx]);
  __syncthreads();
#pragma unroll
  for (int rr = 0; rr < 32; rr += 8) st(&dst[(long)(c0 + ty + rr) * R + r0 + tx], t[tx][ty + rr]);
}

// ---------- row softmax f32 -> bf16, row length PER*256 ----------
template<int PER>
__global__ __launch_bounds__(256) void softmax_k(const float* __restrict__ x,
    unsigned short* __restrict__ y, long bstr) {
  __shared__ float red[4];
  const int L = PER * 256;
  int b = blockIdx.y, r = blockIdx.x, tid = threadIdx.x;
  const float* p = x + (long)b * bstr + (long)r * L;
  unsigned short* o = y + (long)b * bstr + (long)r * L;
  float vals[PER];
  float mx = -1e30f;
#pragma unroll
  for (int t = 0; t < PER; t++) { float v = p[tid + (t << 8)]; vals[t] = v; mx = fmaxf(mx, v); }
  for (int ofs = 32; ofs; ofs >>= 1) mx = fmaxf(mx, __shfl_down(mx, ofs, 64));
  int wid = tid >> 6;
  if ((tid & 63) == 0) red[wid] = mx;
  __syncthreads();
  mx = fmaxf(fmaxf(red[0], red[1]), fmaxf(red[2], red[3]));
  float sm = 0.f;
#pragma unroll
  for (int t = 0; t < PER; t++) { float e = __expf(vals[t] - mx); vals[t] = e; sm += e; }
  sm = bred_sum(sm, red);
  float inv = 1.f / sm;
#pragma unroll
  for (int t = 0; t < PER; t++) o[tid + (t << 8)] = f2b(vals[t] * inv);
}

// ---------- bf16 MFMA GEMM: C[m,n] = sum_k A[m,k]*B[n,k], both k-contig ----------
// 128x128 tile, 4 waves of 64x64, BK=64. global_load_lds staging with
// XOR-swizzled global source (linear LDS dest) + swizzled reads.
// EPI: 0 none; 1 relu(v*sc[n]+bi[n]); 2 v*cscale; 3 v+bi[n]; 4 v+bi[m]
template<int EPI, typename TC>
__global__ __launch_bounds__(256) void gemm_bf16(
    const unsigned short* __restrict__ A, long sA, int lda,
    const unsigned short* __restrict__ B, long sB, int ldb,
    TC* __restrict__ C, long sC, int ldc,
    int M, int N, int K,
    const float* __restrict__ sc, const float* __restrict__ bi, float cscale)
{
  __shared__ short As[128 * 64];
  __shared__ short Bs[128 * 64];
  const int tid = threadIdx.x;
  const int lane = tid & 63, wid = tid >> 6;
  const int wm = wid >> 1, wn = wid & 1;
  const int l15 = lane & 15, l4 = lane >> 4, l7 = lane & 7;
  const int bm = blockIdx.y * 128, bn = blockIdx.x * 128;
  const int srow = lane >> 3;           // 0..7 within staged 8-row group
  A += (long)blockIdx.z * sA; B += (long)blockIdx.z * sB; C += (long)blockIdx.z * sC;
  f32x4 acc[4][4] = {};
  for (int k0 = 0; k0 < K; k0 += 64) {
#pragma unroll
    for (int i = 0; i < 4; i++) {
      int row = (wid * 4 + i) * 8 + srow;             // tile row 0..127
      int gcol = (l7 ^ (row & 7)) * 8;                // swizzled k-chunk
      GLDS16(A + (long)(bm + row) * lda + k0 + gcol, &As[(wid * 4 + i) * 512]);
      GLDS16(B + (long)(bn + row) * ldb + k0 + gcol, &Bs[(wid * 4 + i) * 512]);
    }
    __syncthreads();
#pragma unroll
    for (int ks = 0; ks < 2; ks++) {
      bf16x8 af[4], bfr[4];
#pragma unroll
      for (int t = 0; t < 4; t++) {
        int ra = wm * 64 + t * 16 + l15;
        int rb = wn * 64 + t * 16 + l15;
        int ch = (l4 + 4 * ks) ^ (l15 & 7);
        af[t]  = *(const bf16x8*)&As[ra * 64 + ch * 8];
        bfr[t] = *(const bf16x8*)&Bs[rb * 64 + ch * 8];
      }
#pragma unroll
      for (int i = 0; i < 4; i++)
#pragma unroll
        for (int j2 = 0; j2 < 4; j2++)
          acc[i][j2] = __builtin_amdgcn_mfma_f32_16x16x32_bf16(af[i], bfr[j2], acc[i][j2], 0, 0, 0);
    }
    __syncthreads();
  }
#pragma unroll
  for (int i = 0; i < 4; i++) {
#pragma unroll
    for (int j2 = 0; j2 < 4; j2++) {
      int n = bn + wn * 64 + j2 * 16 + l15;
#pragma unroll
      for (int j = 0; j < 4; j++) {
        int m = bm + wm * 64 + i * 16 + l4 * 4 + j;
        float v = acc[i][j2][j];
        if (EPI == 1) v = fmaxf(fmaf(v, sc[n], bi[n]), 0.f);
        if (EPI == 2) v *= cscale;
        if (EPI == 3) v += bi[n];
        if (EPI == 4) v += bi[m];
        st(&C[(long)m * ldc + n], v);
      }
    }
  }
}

// ---------- flash attention, bf16 MFMA, operand-swapped, 16 q-rows/wave ----------
// qk: [B,S,1024] bf16 (cols 0-511 = q prescaled, 512-1023 = k); vT: [B,512,S] bf16.
// K/V double-buffered in LDS with cross-iteration prefetch (2-phase pipeline).
__global__ __launch_bounds__(256) void attn_flash(
    const unsigned short* __restrict__ qk, const unsigned short* __restrict__ vT,
    float* __restrict__ out, int S)
{
  __shared__ short Ks[2][64 * 128];   // [kv][d], XOR-swizzled 16B chunks
  __shared__ short Vs[2][128 * 64];   // [d][kv], XOR-swizzled
  __shared__ short Ps[4][1024];       // per-wave [16 q][64 kv], XOR-swizzled
  const int tid = threadIdx.x, lane = tid & 63, wid = tid >> 6;
  const int h = blockIdx.y, b = blockIdx.z;
  const int l15 = lane & 15, l4 = lane >> 4, l7 = l15 & 7;
  const long qkb = (long)b * S * 1024;
  const long vbb = (long)b * 512 * S;
  const long obase = (long)b * S * 512;
  const int qr0 = blockIdx.x * 64 + wid * 16;
  const int kr = lane >> 4, kc = lane & 15;   // K staging: 4 rows x 16 chunks
  const int vr = lane >> 3, vc = lane & 7;    // V staging: 8 rows x 8 chunks
  bf16x8 qf[4];
#pragma unroll
  for (int ks = 0; ks < 4; ks++)
    qf[ks] = *(const bf16x8*)(qk + qkb + (long)(qr0 + l15) * 1024 + h * 128 + l4 * 8 + ks * 32);
  f32x4 O[8] = {};
  float m_run = -1e30f, l_run = 0.f;
  const int NT = S >> 6;
  auto stage = [&](int bi, int kt) {
#pragma unroll
    for (int i = 0; i < 4; i++) {
      int krow = wid * 16 + i * 4 + kr;
      GLDS16(qk + qkb + (long)(kt * 64 + krow) * 1024 + 512 + h * 128 + ((kc ^ (krow & 7)) << 3),
             &Ks[bi][(wid * 16 + i * 4) * 128]);
      int vrow = wid * 32 + i * 8 + vr;
      GLDS16(vT + vbb + (long)(h * 128 + vrow) * S + kt * 64 + ((vc ^ (vrow & 7)) << 3),
             &Vs[bi][(wid * 32 + i * 8) * 64]);
    }
  };
  stage(0, 0);
  int cur = 0;
  for (int kt = 0; kt < NT; kt++) {
    __syncthreads();                      // drains prefetch vmcnt; tile `cur` ready
    if (kt + 1 < NT) stage(cur ^ 1, kt + 1);   // prefetch overlaps compute below
    // QK^T (swapped): sacc[f][j] = S[kv = f*16 + l4*4 + j][q = l15]
    f32x4 sacc[4] = {};
    __builtin_amdgcn_s_setprio(1);
#pragma unroll
    for (int f = 0; f < 4; f++) {
      int row = f * 16 + l15;
#pragma unroll
      for (int ks = 0; ks < 4; ks++) {
        bf16x8 kf = *(const bf16x8*)&Ks[cur][row * 128 + (((l4 + 4 * ks) ^ l7) << 3)];
        sacc[f] = __builtin_amdgcn_mfma_f32_16x16x32_bf16(kf, qf[ks], sacc[f], 0, 0, 0);
      }
    }
    __builtin_amdgcn_s_setprio(0);
    float pmax = -1e30f;
#pragma unroll
    for (int f = 0; f < 4; f++)
#pragma unroll
      for (int j = 0; j < 4; j++) pmax = fmaxf(pmax, sacc[f][j]);
    pmax = fmaxf(pmax, __shfl_xor(pmax, 16, 64));
    pmax = fmaxf(pmax, __shfl_xor(pmax, 32, 64));
    // defer-max: only rescale when some row's max grew past threshold
    if (!__all(pmax - m_run <= 8.f)) {
      float m_new = fmaxf(m_run, pmax);
      float corr = __expf(m_run - m_new);
      l_run *= corr; m_run = m_new;
#pragma unroll
      for (int fd = 0; fd < 8; fd++) {
        O[fd][0] *= corr; O[fd][1] *= corr; O[fd][2] *= corr; O[fd][3] *= corr;
      }
    }
    float ts = 0.f;
#pragma unroll
    for (int f = 0; f < 4; f++) {
      ushort4 pw;
#pragma unroll
      for (int j = 0; j < 4; j++) {
        float e = __expf(sacc[f][j] - m_run);
        ts += e;
        ((unsigned short*)&pw)[j] = f2b(e);
      }
      *(ushort4*)&Ps[wid][l15 * 64 + (((2 * f + (l4 >> 1)) ^ l7) << 3) + (l4 & 1) * 4] = pw;
    }
    ts += __shfl_xor(ts, 16, 64);
    ts += __shfl_xor(ts, 32, 64);
    l_run += ts;
    // PV (swapped): O[fd] += V^T[d][kv] * P[q][kv]  (Ps wave-private, no barrier)
    __builtin_amdgcn_s_setprio(1);
#pragma unroll
    for (int ks = 0; ks < 2; ks++) {
      int pch = ((l4 + 4 * ks) ^ l7) << 3;
      bf16x8 pf = *(const bf16x8*)&Ps[wid][l15 * 64 + pch];
#pragma unroll
      for (int fd = 0; fd < 8; fd++) {
        bf16x8 vf = *(const bf16x8*)&Vs[cur][(fd * 16 + l15) * 64 + pch];
        O[fd] = __builtin_amdgcn_mfma_f32_16x16x32_bf16(vf, pf, O[fd], 0, 0, 0);
      }
    }
    __builtin_amdgcn_s_setprio(0);
    cur ^= 1;
  }
  float inv = 1.f / l_run;
  float* op = out + obase + (long)(qr0 + l15) * 512 + h * 128;
#pragma unroll
  for (int fd = 0; fd < 8; fd++) {
    f32x4 ov = O[fd];
    ov[0] *= inv; ov[1] *= inv; ov[2] *= inv; ov[3] *= inv;
    *(f32x4*)&op[fd * 16 + l4 * 4] = ov;
  }
}

// ---------- residual add + LayerNorm over E=512 ----------
template<typename TD>
__global__ __launch_bounds__(256) void add_ln(
    const float* __restrict__ att, const unsigned short* __restrict__ resid,
    const float* __restrict__ g, const float* __restrict__ bt,
    TD* __restrict__ dst, long db, int S)
{
  __shared__ float red[4];
  int b = blockIdx.y, s = blockIdx.x, tid = threadIdx.x;
  const float* ap = att + ((long)b * S + s) * 512;
  const unsigned short* rp = resid + ((long)b * S + s) * 512;
  float y0 = ap[tid] + b2f(rp[tid]);
  float y1 = ap[tid + 256] + b2f(rp[tid + 256]);
  float mu = bred_sum(y0 + y1, red) * (1.f / 512.f);
  float d0 = y0 - mu, d1 = y1 - mu;
  float var = bred_sum(d0 * d0 + d1 * d1, red) * (1.f / 512.f);
  float rsv = rsqrtf(var + LN_EPS);
  TD* dp = dst + (long)b * db + (long)s * 512;
  st(&dp[tid], d0 * rsv * g[tid] + bt[tid]);
  st(&dp[tid + 256], d1 * rsv * g[tid + 256] + bt[tid + 256]);
}

extern "C" void kernel_launch(void* const* d_in, const int* in_sizes, int n_in,
                              void* d_out, int out_size, void* d_ws, size_t ws_size,
                              hipStream_t stream) {
  (void)in_sizes; (void)n_in; (void)out_size; (void)ws_size;
  const float* img = (const float*)d_in[0];
  const float* pts = (const float*)d_in[1];
  const float* w1  = (const float*)d_in[2];
  const float* b1  = (const float*)d_in[3];
  const float* g1  = (const float*)d_in[4];
  const float* be1 = (const float*)d_in[5];
  const float* m1  = (const float*)d_in[6];
  const float* v1  = (const float*)d_in[7];
  const float* w2  = (const float*)d_in[8];
  const float* b2  = (const float*)d_in[9];
  const float* g2  = (const float*)d_in[10];
  const float* be2 = (const float*)d_in[11];
  const float* m2  = (const float*)d_in[12];
  const float* v2  = (const float*)d_in[13];
  const float* qw  = (const float*)d_in[14];
  const float* qb  = (const float*)d_in[15];
  const float* kw  = (const float*)d_in[16];
  const float* kb  = (const float*)d_in[17];
  const float* vw  = (const float*)d_in[18];
  const float* vb  = (const float*)d_in[19];
  const float* lng = (const float*)d_in[20];
  const float* lnb = (const float*)d_in[21];
  float* out = (float*)d_out;
  float* ws  = (float*)d_ws;
  typedef unsigned short u16;

  // ---- arena (f32-slot offsets), total ~157.8 MB ----
  u16*   xTu   = (u16*)ws;                       // [4][3072][512] bf16
  float* phi   = ws;                             // [4][2048][1024] f32
  u16*   y1u   = (u16*)(ws + 8388608);           // [4][3072][1024] bf16
  float* phiT  = ws + 8388608;                   // [4][1024][2048] f32
  u16*   featu = (u16*)(ws + 16777216);          // [4][3072][512] bf16
  u16*   featTu= (u16*)(ws + 19922944);          // [4][512][3072] bf16
  u16*   smI   = (u16*)(ws + 23068672);          // phi_i softmax  [4][2048][1024] bf16
  u16*   smPT  = (u16*)(ws + 27262976);          // phi_p^T softmax [4][1024][2048] bf16
  u16*   Xi    = (u16*)(ws + 31457280);          // [4][1024][512] bf16
  u16*   Xp    = (u16*)(ws + 32505856);          // [4][2048][512] bf16
  u16*   jointu= (u16*)(ws + 34603008);          // [4][3072][512] bf16
  u16*   w1b   = (u16*)(ws + 37748736);
  u16*   w2b   = (u16*)(ws + 38010880);
  u16*   qkwb  = (u16*)(ws + 38273024);          // [3][1024][512] bf16 (q||k, q prescaled)
  u16*   vwb   = (u16*)(ws + 39059456);
  float* s1f   = ws + 39452672;
  float* f1f   = s1f + 1024;
  float* s2f   = f1f + 1024;
  float* f2f   = s2f + 512;
  float* qkbf  = ws + 39455744;                  // [3][1024] f32 bias (q prescaled)
  // attention scratch (A0/B0 regions after phi/phiT are dead)
  u16*   qkbu  = (u16*)ws;                       // [4][S<=3072][1024] bf16
  u16*   vTu   = (u16*)(ws + 6291456);           // [4][512][S] bf16
  float* attf  = ws + 9437184;                   // [4][S][512] f32

  dim3 blk(256);
  fold_bn<<<dim3(4), blk, 0, stream>>>(b1, g1, be1, m1, v1, b2, g2, be2, m2, v2, s1f, f1f, s2f, f2f);
  cvt_bf16<<<dim3(2048), blk, 0, stream>>>(w1, w1b, 524288);
  cvt_bf16<<<dim3(2048), blk, 0, stream>>>(w2, w2b, 524288);
  cvt_bf16<<<dim3(3072), blk, 0, stream>>>(vw, vwb, 786432);
  prep_qk<<<dim3(6144), blk, 0, stream>>>(qw, qb, kw, kb, qkwb, qkbf);

  // xT: [pos, 512] bf16 (points rows 0..2047, img rows 2048..3071)
  transpose_t<float, u16><<<dim3(64, 16, 4), blk, 0, stream>>>(pts, xTu, 512, 2048, 1048576L, 1572864L);
  transpose_t<float, u16><<<dim3(32, 16, 4), blk, 0, stream>>>(img, xTu + 1048576, 512, 1024, 524288L, 1572864L);

  // MLP1: y1[pos,1024] = relu(bn1(xT @ w1^T))
  gemm_bf16<1, u16><<<dim3(8, 24, 4), blk, 0, stream>>>(xTu, 1572864L, 512, w1b, 0L, 512,
      y1u, 3145728L, 1024, 3072, 1024, 512, s1f, f1f, 0.f);
  // MLP2: feat[pos,512]
  gemm_bf16<1, u16><<<dim3(4, 24, 4), blk, 0, stream>>>(y1u, 3145728L, 1024, w2b, 0L, 1024,
      featu, 1572864L, 512, 3072, 512, 1024, s2f, f2f, 0.f);
  // featT [512, 3072]
  transpose_t<u16, u16><<<dim3(16, 96, 4), blk, 0, stream>>>(featu, featTu, 3072, 512, 1572864L, 1572864L);
  // phi[p,i] f32
  gemm_bf16<2, float><<<dim3(8, 16, 4), blk, 0, stream>>>(featu, 1572864L, 512, featu + 1048576, 1572864L, 512,
      phi, 2097152L, 1024, 2048, 1024, 512, nullptr, nullptr, 0.044194173824159216f);
  transpose_t<float, float><<<dim3(32, 64, 4), blk, 0, stream>>>(phi, phiT, 2048, 1024, 2097152L, 2097152L);
  softmax_k<4><<<dim3(2048, 4), blk, 0, stream>>>(phi, smI, 2097152L);    // softmax over i
  softmax_k<8><<<dim3(1024, 4), blk, 0, stream>>>(phiT, smPT, 2097152L);  // softmax over p
  // Xi[i,c] = phi_p^T @ featP^T ; Xp[p,c] = phi_i @ featI^T
  gemm_bf16<0, u16><<<dim3(4, 8, 4), blk, 0, stream>>>(smPT, 2097152L, 2048, featTu, 1572864L, 3072,
      Xi, 524288L, 512, 1024, 512, 2048, nullptr, nullptr, 0.f);
  gemm_bf16<0, u16><<<dim3(4, 16, 4), blk, 0, stream>>>(smI, 2097152L, 1024, featTu + 2048, 1572864L, 3072,
      Xp, 1048576L, 512, 2048, 512, 1024, nullptr, nullptr, 0.f);

  struct AttCfg { const u16* X; int S; int j; };
  AttCfg cfgs[3] = { {Xi, 1024, 0}, {Xp, 2048, 1}, {jointu, 3072, 2} };
  for (int a = 0; a < 3; a++) {
    const u16* X = cfgs[a].X; int S = cfgs[a].S; int j = cfgs[a].j;
    long xs = (long)S * 512;
    // fused QK projection: [S,1024] (q cols 0-511 prescaled, k cols 512-1023)
    gemm_bf16<3, u16><<<dim3(8, S / 128, 4), blk, 0, stream>>>(X, xs, 512, qkwb + j * 524288, 0L, 512,
        qkbu, (long)S * 1024, 1024, S, 1024, 512, nullptr, qkbf + j * 1024, 0.f);
    gemm_bf16<4, u16><<<dim3(S / 128, 4, 4), blk, 0, stream>>>(vwb + j * 262144, 0L, 512, X, xs, 512,
        vTu, xs, S, 512, S, 512, nullptr, vb + j * 512, 0.f);
    attn_flash<<<dim3(S / 64, 4, 4), blk, 0, stream>>>(qkbu, vTu, attf, S);
    if (a == 0)
      add_ln<u16><<<dim3(S, 4), blk, 0, stream>>>(attf, X, lng + j * 512, lnb + j * 512,
          jointu + 1048576, 1572864L, S);
    else if (a == 1)
      add_ln<u16><<<dim3(S, 4), blk, 0, stream>>>(attf, X, lng + j * 512, lnb + j * 512,
          jointu, 1572864L, S);
    else
      add_ln<float><<<dim3(S, 4), blk, 0, stream>>>(attf, X, lng + j * 512, lnb + j * 512,
          out, 1572864L, S);
  }
}

// Round 5
// 551.987 us; speedup vs baseline: 20.1375x; 1.0712x over previous
//
#include <hip/hip_runtime.h>
#include <math.h>

#define LN_EPS 1e-5f

typedef __attribute__((ext_vector_type(8))) short bf16x8;
typedef __attribute__((ext_vector_type(4))) float f32x4;

// async global->LDS, 16B per lane; LDS dest is wave-uniform base + lane*16
#define GLDS16(g, l) __builtin_amdgcn_global_load_lds( \
    (const __attribute__((address_space(1))) unsigned int*)(g), \
    (__attribute__((address_space(3))) unsigned int*)(l), 16, 0, 0)

__device__ __forceinline__ float b2f(unsigned short h) { return __uint_as_float(((unsigned)h) << 16); }
__device__ __forceinline__ unsigned short f2b(float f) {
  unsigned u = __float_as_uint(f);
  unsigned r = (u + 0x7fffu + ((u >> 16) & 1u)) >> 16;
  return (unsigned short)r;
}
__device__ __forceinline__ float ld(const float* p) { return *p; }
__device__ __forceinline__ float ld(const unsigned short* p) { return b2f(*p); }
__device__ __forceinline__ void st(float* p, float v) { *p = v; }
__device__ __forceinline__ void st(unsigned short* p, float v) { *p = f2b(v); }

// ---------- block reduction helpers (256 threads, 4 waves) ----------
__device__ __forceinline__ float bred_sum(float v, float* red) {
  for (int o = 32; o; o >>= 1) v += __shfl_down(v, o, 64);
  int wid = threadIdx.x >> 6;
  __syncthreads();
  if ((threadIdx.x & 63) == 0) red[wid] = v;
  __syncthreads();
  return red[0] + red[1] + red[2] + red[3];
}

// ---------- folded BN ----------
__global__ void fold_bn(const float* b1, const float* g1, const float* be1,
                        const float* m1, const float* v1,
                        const float* b2, const float* g2, const float* be2,
                        const float* m2, const float* v2,
                        float* s1, float* f1, float* s2, float* f2) {
  int t = blockIdx.x * 256 + threadIdx.x;
  if (t < 1024) { float s = g1[t] * rsqrtf(v1[t] + LN_EPS); s1[t] = s; f1[t] = (b1[t] - m1[t]) * s + be1[t]; }
  if (t < 512)  { float s = g2[t] * rsqrtf(v2[t] + LN_EPS); s2[t] = s; f2[t] = (b2[t] - m2[t]) * s + be2[t]; }
}

// ---------- f32 -> bf16 elementwise ----------
__global__ void cvt_bf16(const float* __restrict__ s, unsigned short* __restrict__ d, int n) {
  int i = blockIdx.x * 256 + threadIdx.x;
  if (i < n) d[i] = f2b(s[i]);
}

// ---------- build concatenated QK weights/bias, q-side prescaled by 512^-0.5 ----------
__global__ void prep_qk(const float* __restrict__ qw, const float* __restrict__ qb,
                        const float* __restrict__ kw, const float* __restrict__ kb,
                        unsigned short* __restrict__ qkw, float* __restrict__ qkbias) {
  const float scl = 0.044194173824159216f;
  int idx = blockIdx.x * 256 + threadIdx.x;   // over 3*1024*512
  if (idx < 1572864) {
    int j = idx >> 19; int r = idx & 524287; int n = r >> 9; int k = r & 511;
    float v = (n < 512) ? qw[j * 262144 + n * 512 + k] * scl
                        : kw[j * 262144 + (n - 512) * 512 + k];
    qkw[idx] = f2b(v);
  }
  if (idx < 3072) {
    int j = idx >> 10, n = idx & 1023;
    qkbias[idx] = (n < 512) ? qb[j * 512 + n] * scl : kb[j * 512 + n - 512];
  }
}

// ---------- 32x32 tiled transpose, typed: src[R][Cc] -> dst[Cc][R] ----------
template<typename TS, typename TD>
__global__ __launch_bounds__(256) void transpose_t(const TS* __restrict__ src,
    TD* __restrict__ dst, int R, int Cc, long sS, long sD) {
  __shared__ float t[32][33];
  src += (long)blockIdx.z * sS; dst += (long)blockIdx.z * sD;
  int c0 = blockIdx.x * 32, r0 = blockIdx.y * 32;
  int tx = threadIdx.x & 31, ty = threadIdx.x >> 5;
#pragma unroll
  for (int rr = 0; rr < 32; rr += 8) t[ty + rr][tx] = ld(&src[(long)(r0 + ty + rr) * Cc + c0 + tx]);
  __syncthreads();
#pragma unroll
  for (int rr = 0; rr < 32; rr += 8) st(&dst[(long)(c0 + ty + rr) * R + r0 + tx], t[tx][ty + rr]);
}

// ---------- row softmax f32 -> bf16, row length PER*256 ----------
template<int PER>
__global__ __launch_bounds__(256) void softmax_k(const float* __restrict__ x,
    unsigned short* __restrict__ y, long bstr) {
  __shared__ float red[4];
  const int L = PER * 256;
  int b = blockIdx.y, r = blockIdx.x, tid = threadIdx.x;
  const float* p = x + (long)b * bstr + (long)r * L;
  unsigned short* o = y + (long)b * bstr + (long)r * L;
  float vals[PER];
  float mx = -1e30f;
#pragma unroll
  for (int t = 0; t < PER; t++) { float v = p[tid + (t << 8)]; vals[t] = v; mx = fmaxf(mx, v); }
  for (int ofs = 32; ofs; ofs >>= 1) mx = fmaxf(mx, __shfl_down(mx, ofs, 64));
  int wid = tid >> 6;
  if ((tid & 63) == 0) red[wid] = mx;
  __syncthreads();
  mx = fmaxf(fmaxf(red[0], red[1]), fmaxf(red[2], red[3]));
  float sm = 0.f;
#pragma unroll
  for (int t = 0; t < PER; t++) { float e = __expf(vals[t] - mx); vals[t] = e; sm += e; }
  sm = bred_sum(sm, red);
  float inv = 1.f / sm;
#pragma unroll
  for (int t = 0; t < PER; t++) o[tid + (t << 8)] = f2b(vals[t] * inv);
}

// ---------- bf16 MFMA GEMM: C[m,n] = sum_k A[m,k]*B[n,k], both k-contig ----------
// 128x128 tile, 4 waves of 64x64, BK=64. global_load_lds staging with
// XOR-swizzled global source (linear LDS dest) + swizzled reads.
// EPI: 0 none; 1 relu(v*sc[n]+bi[n]); 2 v*cscale; 3 v+bi[n]; 4 v+bi[m]
template<int EPI, typename TC>
__global__ __launch_bounds__(256) void gemm_bf16(
    const unsigned short* __restrict__ A, long sA, int lda,
    const unsigned short* __restrict__ B, long sB, int ldb,
    TC* __restrict__ C, long sC, int ldc,
    int M, int N, int K,
    const float* __restrict__ sc, const float* __restrict__ bi, float cscale)
{
  __shared__ short As[128 * 64];
  __shared__ short Bs[128 * 64];
  const int tid = threadIdx.x;
  const int lane = tid & 63, wid = tid >> 6;
  const int wm = wid >> 1, wn = wid & 1;
  const int l15 = lane & 15, l4 = lane >> 4, l7 = lane & 7;
  const int bm = blockIdx.y * 128, bn = blockIdx.x * 128;
  const int srow = lane >> 3;           // 0..7 within staged 8-row group
  A += (long)blockIdx.z * sA; B += (long)blockIdx.z * sB; C += (long)blockIdx.z * sC;
  f32x4 acc[4][4] = {};
  for (int k0 = 0; k0 < K; k0 += 64) {
#pragma unroll
    for (int i = 0; i < 4; i++) {
      int row = (wid * 4 + i) * 8 + srow;             // tile row 0..127
      int gcol = (l7 ^ (row & 7)) * 8;                // swizzled k-chunk
      GLDS16(A + (long)(bm + row) * lda + k0 + gcol, &As[(wid * 4 + i) * 512]);
      GLDS16(B + (long)(bn + row) * ldb + k0 + gcol, &Bs[(wid * 4 + i) * 512]);
    }
    __syncthreads();
#pragma unroll
    for (int ks = 0; ks < 2; ks++) {
      bf16x8 af[4], bfr[4];
#pragma unroll
      for (int t = 0; t < 4; t++) {
        int ra = wm * 64 + t * 16 + l15;
        int rb = wn * 64 + t * 16 + l15;
        int ch = (l4 + 4 * ks) ^ (l15 & 7);
        af[t]  = *(const bf16x8*)&As[ra * 64 + ch * 8];
        bfr[t] = *(const bf16x8*)&Bs[rb * 64 + ch * 8];
      }
#pragma unroll
      for (int i = 0; i < 4; i++)
#pragma unroll
        for (int j2 = 0; j2 < 4; j2++)
          acc[i][j2] = __builtin_amdgcn_mfma_f32_16x16x32_bf16(af[i], bfr[j2], acc[i][j2], 0, 0, 0);
    }
    __syncthreads();
  }
#pragma unroll
  for (int i = 0; i < 4; i++) {
#pragma unroll
    for (int j2 = 0; j2 < 4; j2++) {
      int n = bn + wn * 64 + j2 * 16 + l15;
#pragma unroll
      for (int j = 0; j < 4; j++) {
        int m = bm + wm * 64 + i * 16 + l4 * 4 + j;
        float v = acc[i][j2][j];
        if (EPI == 1) v = fmaxf(fmaf(v, sc[n], bi[n]), 0.f);
        if (EPI == 2) v *= cscale;
        if (EPI == 3) v += bi[n];
        if (EPI == 4) v += bi[m];
        st(&C[(long)m * ldc + n], v);
      }
    }
  }
}

// ---------- flash attention, bf16 MFMA, operand-swapped ----------
// 512 threads = 8 waves, 16 q-rows/wave -> 128 q-rows/block.
// qk: [B,S,1024] bf16 (cols 0-511 = q prescaled, 512-1023 = k); vT: [B,512,S] bf16.
// K/V double-buffered in LDS (shared by all 8 waves) with cross-iteration prefetch.
__global__ __launch_bounds__(512) void attn_flash(
    const unsigned short* __restrict__ qk, const unsigned short* __restrict__ vT,
    float* __restrict__ out, int S)
{
  __shared__ short Ks[2][64 * 128];   // [kv][d], XOR-swizzled 16B chunks (32 KB)
  __shared__ short Vs[2][128 * 64];   // [d][kv], XOR-swizzled (32 KB)
  __shared__ short Ps[8][1024];       // per-wave [16 q][64 kv], XOR-swizzled (16 KB)
  const int tid = threadIdx.x, lane = tid & 63, wid = tid >> 6;   // 8 waves
  const int h = blockIdx.y, b = blockIdx.z;
  const int l15 = lane & 15, l4 = lane >> 4, l7 = l15 & 7;
  const long qkb = (long)b * S * 1024;
  const long vbb = (long)b * 512 * S;
  const long obase = (long)b * S * 512;
  const int qr0 = blockIdx.x * 128 + wid * 16;
  bf16x8 qf[4];
#pragma unroll
  for (int ks = 0; ks < 4; ks++)
    qf[ks] = *(const bf16x8*)(qk + qkb + (long)(qr0 + l15) * 1024 + h * 128 + l4 * 8 + ks * 32);
  f32x4 O[8] = {};
  float m_run = -1e30f, l_run = 0.f;
  const int NT = S >> 6;
  auto stage = [&](int bi, int kt) {
#pragma unroll
    for (int i = 0; i < 2; i++) {
      int krow = wid * 8 + i * 4 + (lane >> 4);       // 4 rows per issue
      GLDS16(qk + qkb + (long)(kt * 64 + krow) * 1024 + 512 + h * 128 + (((lane & 15) ^ (krow & 7)) << 3),
             &Ks[bi][(wid * 8 + i * 4) * 128]);
      int vrow = wid * 16 + i * 8 + (lane >> 3);      // 8 rows per issue
      GLDS16(vT + vbb + (long)(h * 128 + vrow) * S + kt * 64 + (((lane & 7) ^ (vrow & 7)) << 3),
             &Vs[bi][(wid * 16 + i * 8) * 64]);
    }
  };
  stage(0, 0);
  int cur = 0;
  for (int kt = 0; kt < NT; kt++) {
    __syncthreads();                      // drains prefetch vmcnt; tile `cur` ready
    if (kt + 1 < NT) stage(cur ^ 1, kt + 1);   // prefetch overlaps compute below
    // QK^T (swapped): sacc[f][j] = S[kv = f*16 + l4*4 + j][q = l15]
    f32x4 sacc[4] = {};
    __builtin_amdgcn_s_setprio(1);
#pragma unroll
    for (int f = 0; f < 4; f++) {
      int row = f * 16 + l15;
#pragma unroll
      for (int ks = 0; ks < 4; ks++) {
        bf16x8 kf = *(const bf16x8*)&Ks[cur][row * 128 + (((l4 + 4 * ks) ^ l7) << 3)];
        sacc[f] = __builtin_amdgcn_mfma_f32_16x16x32_bf16(kf, qf[ks], sacc[f], 0, 0, 0);
      }
    }
    __builtin_amdgcn_s_setprio(0);
    float pmax = -1e30f;
#pragma unroll
    for (int f = 0; f < 4; f++)
#pragma unroll
      for (int j = 0; j < 4; j++) pmax = fmaxf(pmax, sacc[f][j]);
    pmax = fmaxf(pmax, __shfl_xor(pmax, 16, 64));
    pmax = fmaxf(pmax, __shfl_xor(pmax, 32, 64));
    // defer-max: only rescale when some row's max grew past threshold
    if (!__all(pmax - m_run <= 8.f)) {
      float m_new = fmaxf(m_run, pmax);
      float corr = __expf(m_run - m_new);
      l_run *= corr; m_run = m_new;
#pragma unroll
      for (int fd = 0; fd < 8; fd++) {
        O[fd][0] *= corr; O[fd][1] *= corr; O[fd][2] *= corr; O[fd][3] *= corr;
      }
    }
    float ts = 0.f;
#pragma unroll
    for (int f = 0; f < 4; f++) {
      ushort4 pw;
#pragma unroll
      for (int j = 0; j < 4; j++) {
        float e = __expf(sacc[f][j] - m_run);
        ts += e;
        ((unsigned short*)&pw)[j] = f2b(e);
      }
      *(ushort4*)&Ps[wid][l15 * 64 + (((2 * f + (l4 >> 1)) ^ l7) << 3) + (l4 & 1) * 4] = pw;
    }
    ts += __shfl_xor(ts, 16, 64);
    ts += __shfl_xor(ts, 32, 64);
    l_run += ts;
    // PV (swapped): O[fd] += V^T[d][kv] * P[q][kv]  (Ps wave-private, no barrier)
    __builtin_amdgcn_s_setprio(1);
#pragma unroll
    for (int ks = 0; ks < 2; ks++) {
      int pch = ((l4 + 4 * ks) ^ l7) << 3;
      bf16x8 pf = *(const bf16x8*)&Ps[wid][l15 * 64 + pch];
#pragma unroll
      for (int fd = 0; fd < 8; fd++) {
        bf16x8 vf = *(const bf16x8*)&Vs[cur][(fd * 16 + l15) * 64 + pch];
        O[fd] = __builtin_amdgcn_mfma_f32_16x16x32_bf16(vf, pf, O[fd], 0, 0, 0);
      }
    }
    __builtin_amdgcn_s_setprio(0);
    cur ^= 1;
  }
  float inv = 1.f / l_run;
  float* op = out + obase + (long)(qr0 + l15) * 512 + h * 128;
#pragma unroll
  for (int fd = 0; fd < 8; fd++) {
    f32x4 ov = O[fd];
    ov[0] *= inv; ov[1] *= inv; ov[2] *= inv; ov[3] *= inv;
    *(f32x4*)&op[fd * 16 + l4 * 4] = ov;
  }
}

// ---------- residual add + LayerNorm over E=512 ----------
template<typename TD>
__global__ __launch_bounds__(256) void add_ln(
    const float* __restrict__ att, const unsigned short* __restrict__ resid,
    const float* __restrict__ g, const float* __restrict__ bt,
    TD* __restrict__ dst, long db, int S)
{
  __shared__ float red[4];
  int b = blockIdx.y, s = blockIdx.x, tid = threadIdx.x;
  const float* ap = att + ((long)b * S + s) * 512;
  const unsigned short* rp = resid + ((long)b * S + s) * 512;
  float y0 = ap[tid] + b2f(rp[tid]);
  float y1 = ap[tid + 256] + b2f(rp[tid + 256]);
  float mu = bred_sum(y0 + y1, red) * (1.f / 512.f);
  float d0 = y0 - mu, d1 = y1 - mu;
  float var = bred_sum(d0 * d0 + d1 * d1, red) * (1.f / 512.f);
  float rsv = rsqrtf(var + LN_EPS);
  TD* dp = dst + (long)b * db + (long)s * 512;
  st(&dp[tid], d0 * rsv * g[tid] + bt[tid]);
  st(&dp[tid + 256], d1 * rsv * g[tid + 256] + bt[tid + 256]);
}

extern "C" void kernel_launch(void* const* d_in, const int* in_sizes, int n_in,
                              void* d_out, int out_size, void* d_ws, size_t ws_size,
                              hipStream_t stream) {
  (void)in_sizes; (void)n_in; (void)out_size; (void)ws_size;
  const float* img = (const float*)d_in[0];
  const float* pts = (const float*)d_in[1];
  const float* w1  = (const float*)d_in[2];
  const float* b1  = (const float*)d_in[3];
  const float* g1  = (const float*)d_in[4];
  const float* be1 = (const float*)d_in[5];
  const float* m1  = (const float*)d_in[6];
  const float* v1  = (const float*)d_in[7];
  const float* w2  = (const float*)d_in[8];
  const float* b2  = (const float*)d_in[9];
  const float* g2  = (const float*)d_in[10];
  const float* be2 = (const float*)d_in[11];
  const float* m2  = (const float*)d_in[12];
  const float* v2  = (const float*)d_in[13];
  const float* qw  = (const float*)d_in[14];
  const float* qb  = (const float*)d_in[15];
  const float* kw  = (const float*)d_in[16];
  const float* kb  = (const float*)d_in[17];
  const float* vw  = (const float*)d_in[18];
  const float* vb  = (const float*)d_in[19];
  const float* lng = (const float*)d_in[20];
  const float* lnb = (const float*)d_in[21];
  float* out = (float*)d_out;
  float* ws  = (float*)d_ws;
  typedef unsigned short u16;

  // ---- arena (f32-slot offsets), total ~157.8 MB ----
  u16*   xTu   = (u16*)ws;                       // [4][3072][512] bf16
  float* phi   = ws;                             // [4][2048][1024] f32
  u16*   y1u   = (u16*)(ws + 8388608);           // [4][3072][1024] bf16
  float* phiT  = ws + 8388608;                   // [4][1024][2048] f32
  u16*   featu = (u16*)(ws + 16777216);          // [4][3072][512] bf16
  u16*   featTu= (u16*)(ws + 19922944);          // [4][512][3072] bf16
  u16*   smI   = (u16*)(ws + 23068672);          // phi_i softmax  [4][2048][1024] bf16
  u16*   smPT  = (u16*)(ws + 27262976);          // phi_p^T softmax [4][1024][2048] bf16
  u16*   Xi    = (u16*)(ws + 31457280);          // [4][1024][512] bf16
  u16*   Xp    = (u16*)(ws + 32505856);          // [4][2048][512] bf16
  u16*   jointu= (u16*)(ws + 34603008);          // [4][3072][512] bf16
  u16*   w1b   = (u16*)(ws + 37748736);
  u16*   w2b   = (u16*)(ws + 38010880);
  u16*   qkwb  = (u16*)(ws + 38273024);          // [3][1024][512] bf16 (q||k, q prescaled)
  u16*   vwb   = (u16*)(ws + 39059456);
  float* s1f   = ws + 39452672;
  float* f1f   = s1f + 1024;
  float* s2f   = f1f + 1024;
  float* f2f   = s2f + 512;
  float* qkbf  = ws + 39455744;                  // [3][1024] f32 bias (q prescaled)
  // attention scratch (A0/B0 regions after phi/phiT are dead)
  u16*   qkbu  = (u16*)ws;                       // [4][S<=3072][1024] bf16
  u16*   vTu   = (u16*)(ws + 6291456);           // [4][512][S] bf16
  float* attf  = ws + 9437184;                   // [4][S][512] f32

  dim3 blk(256);
  fold_bn<<<dim3(4), blk, 0, stream>>>(b1, g1, be1, m1, v1, b2, g2, be2, m2, v2, s1f, f1f, s2f, f2f);
  cvt_bf16<<<dim3(2048), blk, 0, stream>>>(w1, w1b, 524288);
  cvt_bf16<<<dim3(2048), blk, 0, stream>>>(w2, w2b, 524288);
  cvt_bf16<<<dim3(3072), blk, 0, stream>>>(vw, vwb, 786432);
  prep_qk<<<dim3(6144), blk, 0, stream>>>(qw, qb, kw, kb, qkwb, qkbf);

  // xT: [pos, 512] bf16 (points rows 0..2047, img rows 2048..3071)
  transpose_t<float, u16><<<dim3(64, 16, 4), blk, 0, stream>>>(pts, xTu, 512, 2048, 1048576L, 1572864L);
  transpose_t<float, u16><<<dim3(32, 16, 4), blk, 0, stream>>>(img, xTu + 1048576, 512, 1024, 524288L, 1572864L);

  // MLP1: y1[pos,1024] = relu(bn1(xT @ w1^T))
  gemm_bf16<1, u16><<<dim3(8, 24, 4), blk, 0, stream>>>(xTu, 1572864L, 512, w1b, 0L, 512,
      y1u, 3145728L, 1024, 3072, 1024, 512, s1f, f1f, 0.f);
  // MLP2: feat[pos,512]
  gemm_bf16<1, u16><<<dim3(4, 24, 4), blk, 0, stream>>>(y1u, 3145728L, 1024, w2b, 0L, 1024,
      featu, 1572864L, 512, 3072, 512, 1024, s2f, f2f, 0.f);
  // featT [512, 3072]
  transpose_t<u16, u16><<<dim3(16, 96, 4), blk, 0, stream>>>(featu, featTu, 3072, 512, 1572864L, 1572864L);
  // phi[p,i] f32
  gemm_bf16<2, float><<<dim3(8, 16, 4), blk, 0, stream>>>(featu, 1572864L, 512, featu + 1048576, 1572864L, 512,
      phi, 2097152L, 1024, 2048, 1024, 512, nullptr, nullptr, 0.044194173824159216f);
  transpose_t<float, float><<<dim3(32, 64, 4), blk, 0, stream>>>(phi, phiT, 2048, 1024, 2097152L, 2097152L);
  softmax_k<4><<<dim3(2048, 4), blk, 0, stream>>>(phi, smI, 2097152L);    // softmax over i
  softmax_k<8><<<dim3(1024, 4), blk, 0, stream>>>(phiT, smPT, 2097152L);  // softmax over p
  // Xi[i,c] = phi_p^T @ featP^T ; Xp[p,c] = phi_i @ featI^T
  gemm_bf16<0, u16><<<dim3(4, 8, 4), blk, 0, stream>>>(smPT, 2097152L, 2048, featTu, 1572864L, 3072,
      Xi, 524288L, 512, 1024, 512, 2048, nullptr, nullptr, 0.f);
  gemm_bf16<0, u16><<<dim3(4, 16, 4), blk, 0, stream>>>(smI, 2097152L, 1024, featTu + 2048, 1572864L, 3072,
      Xp, 1048576L, 512, 2048, 512, 1024, nullptr, nullptr, 0.f);

  struct AttCfg { const u16* X; int S; int j; };
  AttCfg cfgs[3] = { {Xi, 1024, 0}, {Xp, 2048, 1}, {jointu, 3072, 2} };
  for (int a = 0; a < 3; a++) {
    const u16* X = cfgs[a].X; int S = cfgs[a].S; int j = cfgs[a].j;
    long xs = (long)S * 512;
    // fused QK projection: [S,1024] (q cols 0-511 prescaled, k cols 512-1023)
    gemm_bf16<3, u16><<<dim3(8, S / 128, 4), blk, 0, stream>>>(X, xs, 512, qkwb + j * 524288, 0L, 512,
        qkbu, (long)S * 1024, 1024, S, 1024, 512, nullptr, qkbf + j * 1024, 0.f);
    gemm_bf16<4, u16><<<dim3(S / 128, 4, 4), blk, 0, stream>>>(vwb + j * 262144, 0L, 512, X, xs, 512,
        vTu, xs, S, 512, S, 512, nullptr, vb + j * 512, 0.f);
    attn_flash<<<dim3(S / 128, 4, 4), dim3(512), 0, stream>>>(qkbu, vTu, attf, S);
    if (a == 0)
      add_ln<u16><<<dim3(S, 4), blk, 0, stream>>>(attf, X, lng + j * 512, lnb + j * 512,
          jointu + 1048576, 1572864L, S);
    else if (a == 1)
      add_ln<u16><<<dim3(S, 4), blk, 0, stream>>>(attf, X, lng + j * 512, lnb + j * 512,
          jointu, 1572864L, S);
    else
      add_ln<float><<<dim3(S, 4), blk, 0, stream>>>(attf, X, lng + j * 512, lnb + j * 512,
          out, 1572864L, S);
  }
}